// Round 1
// 11494.709 us; speedup vs baseline: 1.5279x; 1.5279x over previous
//
#include <hip/hip_runtime.h>

// ---------------------------------------------------------------------------
// CoLA forward on MI355X — round 3: move the relational-head GEMMs (terminal,
// tolerance-checked outputs) onto the matrix cores via fp32->f16 hi/lo x3
// emulation (hi*hi + hi*lo + lo*hi, fp32 accum), and dedupe the 24 per-head
// qkv projections into ONE batched GEMM over the 10 distinct inputs.
// The selection-critical chain (embed conv -> cas -> actionness) stays on the
// fp64-accumulated fp32 path to preserve top-k ordering.
// ---------------------------------------------------------------------------

static __device__ __forceinline__ float leaky_f(float x) { return x >= 0.f ? x : 0.2f * x; }

typedef _Float16 f16;
typedef f16 f16x4 __attribute__((ext_vector_type(4)));
typedef f16 f16x8 __attribute__((ext_vector_type(8)));
typedef float f32x4 __attribute__((ext_vector_type(4)));

// ---------- pack (N,KC,taps) -> (taps,N,KC) ----------
__global__ __launch_bounds__(256) void pack_w_k(const float* __restrict__ src,
                                                float* __restrict__ dst,
                                                int N, int KC, int taps) {
  long total = (long)N * KC * taps;
  long i = (long)blockIdx.x * 256 + threadIdx.x;
  if (i >= total) return;
  long nk = (long)N * KC;
  int tap = (int)(i / nk);
  long rem = i - (long)tap * nk;
  int n = (int)(rem / KC);
  int k = (int)(rem - (long)n * KC);
  dst[i] = src[((long)n * KC + k) * taps + tap];
}

// ---------- generic 64x64 fp32 GEMM / k3-conv:  C = act(A*B^T + bias) ----------
// DACC=1: per-K-tile fp32 partial added into fp64 accumulator (accuracy for
// the selection-critical path).
template <int DACC>
__global__ __launch_bounds__(256) void gemm64_k(
    const float* __restrict__ A, const float* __restrict__ Bw,
    const float* __restrict__ bias, float* __restrict__ C,
    int M, int N, int KC, int taps, int shift_base,
    int a_grp, long a_bstride, int c_grp, long c_bstride, int act) {
  __shared__ __align__(16) float As[16][68];
  __shared__ __align__(16) float Bs[16][68];
  int tid = threadIdx.x;
  int n0 = blockIdx.x * 64, m0 = blockIdx.y * 64;
  int tx = tid & 15, ty = tid >> 4;
  int row_l = tid >> 2;
  int kq = (tid & 3) << 2;
  float accf[4][4] = {{0.f}};
  double accd[4][4];
  if (DACC) {
#pragma unroll
    for (int i = 0; i < 4; ++i)
#pragma unroll
      for (int j = 0; j < 4; ++j) accd[i][j] = 0.0;
  }
  int tpt = KC >> 4;           // K-tiles per tap
  int nkt = tpt * taps;
  int am = m0 + row_l;
  int agrp = 0, ar = 0;
  if (am < M) { agrp = am / a_grp; ar = am - agrp * a_grp; }
  int bn = n0 + row_l;
  for (int kt = 0; kt < nkt; ++kt) {
    int tap = kt / tpt;
    int k0 = (kt - tap * tpt) << 4;
    float4 av = make_float4(0.f, 0.f, 0.f, 0.f);
    float4 bv = make_float4(0.f, 0.f, 0.f, 0.f);
    if (am < M) {
      int rr = ar + tap + shift_base;
      if (rr >= 0 && rr < a_grp)
        av = *(const float4*)(A + (long)agrp * a_bstride + (long)rr * KC + (k0 + kq));
    }
    if (bn < N)
      bv = *(const float4*)(Bw + ((long)tap * N + bn) * KC + (k0 + kq));
    __syncthreads();
    As[kq + 0][row_l] = av.x; As[kq + 1][row_l] = av.y;
    As[kq + 2][row_l] = av.z; As[kq + 3][row_l] = av.w;
    Bs[kq + 0][row_l] = bv.x; Bs[kq + 1][row_l] = bv.y;
    Bs[kq + 2][row_l] = bv.z; Bs[kq + 3][row_l] = bv.w;
    __syncthreads();
    float tile[4][4];
    if (DACC) {
#pragma unroll
      for (int i = 0; i < 4; ++i)
#pragma unroll
        for (int j = 0; j < 4; ++j) tile[i][j] = 0.f;
    }
#pragma unroll
    for (int k = 0; k < 16; ++k) {
      float4 a4 = *(const float4*)&As[k][ty << 2];
      float4 b4 = *(const float4*)&Bs[k][tx << 2];
      float ar4[4] = {a4.x, a4.y, a4.z, a4.w};
      float br4[4] = {b4.x, b4.y, b4.z, b4.w};
#pragma unroll
      for (int i = 0; i < 4; ++i)
#pragma unroll
        for (int j = 0; j < 4; ++j) {
          if (DACC) tile[i][j] = fmaf(ar4[i], br4[j], tile[i][j]);
          else      accf[i][j] = fmaf(ar4[i], br4[j], accf[i][j]);
        }
    }
    if (DACC) {
#pragma unroll
      for (int i = 0; i < 4; ++i)
#pragma unroll
        for (int j = 0; j < 4; ++j) accd[i][j] += (double)tile[i][j];
    }
  }
#pragma unroll
  for (int i = 0; i < 4; ++i) {
    int m = m0 + (ty << 2) + i;
    if (m >= M) continue;
    int grp = m / c_grp, r = m - grp * c_grp;
    float* crow = C + (long)grp * c_bstride + (long)r * N;
#pragma unroll
    for (int j = 0; j < 4; ++j) {
      int n = n0 + (tx << 2) + j;
      if (n >= N) continue;
      float v = DACC ? (float)accd[i][j] : accf[i][j];
      if (bias) v += bias[n];
      if (act == 1) v = fmaxf(v, 0.f);
      else if (act == 2) v = leaky_f(v);
      crow[n] = v;
    }
  }
}

// ---------- 32x32 fp32 GEMM variant (small N), K-tile 32 ----------
template <int DACC>
__global__ __launch_bounds__(256) void gemm32_k(
    const float* __restrict__ A, const float* __restrict__ Bw,
    const float* __restrict__ bias, float* __restrict__ C,
    int M, int N, int KC, int taps, int shift_base,
    int a_grp, long a_bstride, int c_grp, long c_bstride, int act) {
  __shared__ __align__(16) float As[32][36];
  __shared__ __align__(16) float Bs[32][36];
  int tid = threadIdx.x;
  int n0 = blockIdx.x * 32, m0 = blockIdx.y * 32;
  int tx = tid & 15, ty = tid >> 4;
  int row_l = tid >> 3;          // 0..31
  int kq = (tid & 7) << 2;       // 0..28
  float accf[2][2] = {{0.f}};
  double accd[2][2];
  if (DACC) { accd[0][0] = accd[0][1] = accd[1][0] = accd[1][1] = 0.0; }
  int tpt = KC >> 5;
  int nkt = tpt * taps;
  int am = m0 + row_l;
  int agrp = 0, ar = 0;
  if (am < M) { agrp = am / a_grp; ar = am - agrp * a_grp; }
  int bn = n0 + row_l;
  for (int kt = 0; kt < nkt; ++kt) {
    int tap = kt / tpt;
    int k0 = (kt - tap * tpt) << 5;
    float4 av = make_float4(0.f, 0.f, 0.f, 0.f);
    float4 bv = make_float4(0.f, 0.f, 0.f, 0.f);
    if (am < M) {
      int rr = ar + tap + shift_base;
      if (rr >= 0 && rr < a_grp)
        av = *(const float4*)(A + (long)agrp * a_bstride + (long)rr * KC + (k0 + kq));
    }
    if (bn < N)
      bv = *(const float4*)(Bw + ((long)tap * N + bn) * KC + (k0 + kq));
    __syncthreads();
    As[kq + 0][row_l] = av.x; As[kq + 1][row_l] = av.y;
    As[kq + 2][row_l] = av.z; As[kq + 3][row_l] = av.w;
    Bs[kq + 0][row_l] = bv.x; Bs[kq + 1][row_l] = bv.y;
    Bs[kq + 2][row_l] = bv.z; Bs[kq + 3][row_l] = bv.w;
    __syncthreads();
    float tile[2][2] = {{0.f, 0.f}, {0.f, 0.f}};
#pragma unroll
    for (int k = 0; k < 32; ++k) {
      float2 a2 = *(const float2*)&As[k][ty << 1];
      float2 b2 = *(const float2*)&Bs[k][tx << 1];
      if (DACC) {
        tile[0][0] = fmaf(a2.x, b2.x, tile[0][0]);
        tile[0][1] = fmaf(a2.x, b2.y, tile[0][1]);
        tile[1][0] = fmaf(a2.y, b2.x, tile[1][0]);
        tile[1][1] = fmaf(a2.y, b2.y, tile[1][1]);
      } else {
        accf[0][0] = fmaf(a2.x, b2.x, accf[0][0]);
        accf[0][1] = fmaf(a2.x, b2.y, accf[0][1]);
        accf[1][0] = fmaf(a2.y, b2.x, accf[1][0]);
        accf[1][1] = fmaf(a2.y, b2.y, accf[1][1]);
      }
    }
    if (DACC) {
      accd[0][0] += (double)tile[0][0]; accd[0][1] += (double)tile[0][1];
      accd[1][0] += (double)tile[1][0]; accd[1][1] += (double)tile[1][1];
    }
  }
#pragma unroll
  for (int i = 0; i < 2; ++i) {
    int m = m0 + (ty << 1) + i;
    if (m >= M) continue;
    int grp = m / c_grp, r = m - grp * c_grp;
    float* crow = C + (long)grp * c_bstride + (long)r * N;
#pragma unroll
    for (int j = 0; j < 2; ++j) {
      int n = n0 + (tx << 1) + j;
      if (n >= N) continue;
      float v = DACC ? (float)accd[i][j] : accf[i][j];
      if (bias) v += bias[n];
      if (act == 1) v = fmaxf(v, 0.f);
      else if (act == 2) v = leaky_f(v);
      crow[n] = v;
    }
  }
}

// ---------------------------------------------------------------------------
// MFMA f16x3 GEMM: C[M][N] = A[M][K] * Bw[N][K]^T + bias, fp32-faithful via
// hi/lo f16 split (3 mfma per 16x16x32 tile). 128x128 tile, 4 waves, each
// wave does a 64x64 sub-tile (4x4 frags). K multiple of 32.
// AMODE 0: A rows contiguous (stride K).
// AMODE 1: A rows are the 10 distinct head inputs living in `out`:
//   input i = m/592, b = (m%592)/37, r = m%37
//   i<4 : ea_i  at oEA + i*37*2048,     batch stride 150*2048
//   i<8 : eb_i  at oEB + (i-4)*37*2048, batch stride 150*2048
//   i=8 : hA at oHA, i=9 : hB at oHB,   batch stride 37*2048
// ---------------------------------------------------------------------------
template <int AMODE>
__global__ __launch_bounds__(256) void gemmx3_k(
    const float* __restrict__ Abase, const float* __restrict__ Bw,
    const float* __restrict__ bias, float* __restrict__ C,
    int M, int N, int K,
    long oEA, long oEB, long oHA, long oHB) {
  // stride 40 halves = 80B: 16B-aligned rows, 2-way (free) read conflicts
  __shared__ _Float16 Ah[128][40];
  __shared__ _Float16 Al[128][40];
  __shared__ _Float16 Bh[128][40];
  __shared__ _Float16 Bl[128][40];
  int t = threadIdx.x;
  int m0 = blockIdx.y * 128, n0 = blockIdx.x * 128;

  // staging assignment: thread t loads rows {p*32 + (t>>3)}, float4 col t&7
  int lr = t >> 3;
  int lq = t & 7;
  const float* arow[4];
  const float* brow[4];
#pragma unroll
  for (int p = 0; p < 4; ++p) {
    int m = m0 + p * 32 + lr;
    if (m < M) {
      if (AMODE == 0) {
        arow[p] = Abase + (long)m * K;
      } else {
        int inp = m / 592;
        int rem = m - inp * 592;
        int b = rem / 37;
        int r = rem - b * 37;
        long base, bstr;
        if (inp < 8) { base = (inp < 4 ? oEA : oEB) + (long)(inp & 3) * (37L * 2048); bstr = 150L * 2048; }
        else         { base = (inp == 8) ? oHA : oHB; bstr = 37L * 2048; }
        arow[p] = Abase + base + (long)b * bstr + (long)r * 2048;
      }
    } else arow[p] = nullptr;
    int n = n0 + p * 32 + lr;
    brow[p] = (n < N) ? (Bw + (long)n * K) : nullptr;
  }

  int lane = t & 63;
  int wv = t >> 6;
  int wm = (wv >> 1) * 64, wn = (wv & 1) * 64;
  int fr = lane & 15, fg = lane >> 4;

  f32x4 acc[4][4];
#pragma unroll
  for (int i = 0; i < 4; ++i)
#pragma unroll
    for (int j = 0; j < 4; ++j) acc[i][j] = (f32x4)(0.f);

  int nkt = K >> 5;
  for (int kt = 0; kt < nkt; ++kt) {
    int k0 = kt << 5;
    float4 av[4], bv[4];
#pragma unroll
    for (int p = 0; p < 4; ++p) {
      av[p] = arow[p] ? *(const float4*)(arow[p] + k0 + lq * 4) : make_float4(0.f, 0.f, 0.f, 0.f);
      bv[p] = brow[p] ? *(const float4*)(brow[p] + k0 + lq * 4) : make_float4(0.f, 0.f, 0.f, 0.f);
    }
    __syncthreads();   // previous iteration's frag reads done
#pragma unroll
    for (int p = 0; p < 4; ++p) {
      int row = p * 32 + lr;
      float xs[4] = {av[p].x, av[p].y, av[p].z, av[p].w};
      f16x4 h, l;
#pragma unroll
      for (int e = 0; e < 4; ++e) {
        f16 hh = (f16)xs[e];
        h[e] = hh;
        l[e] = (f16)(xs[e] - (float)hh);   // exact residual, then round
      }
      *(f16x4*)&Ah[row][lq * 4] = h;
      *(f16x4*)&Al[row][lq * 4] = l;
      float ys[4] = {bv[p].x, bv[p].y, bv[p].z, bv[p].w};
#pragma unroll
      for (int e = 0; e < 4; ++e) {
        f16 hh = (f16)ys[e];
        h[e] = hh;
        l[e] = (f16)(ys[e] - (float)hh);
      }
      *(f16x4*)&Bh[row][lq * 4] = h;
      *(f16x4*)&Bl[row][lq * 4] = l;
    }
    __syncthreads();
    f16x8 ah[4], alo[4], bh[4], blo[4];
#pragma unroll
    for (int i = 0; i < 4; ++i) {
      ah[i]  = *(const f16x8*)&Ah[wm + i * 16 + fr][fg * 8];
      alo[i] = *(const f16x8*)&Al[wm + i * 16 + fr][fg * 8];
      bh[i]  = *(const f16x8*)&Bh[wn + i * 16 + fr][fg * 8];
      blo[i] = *(const f16x8*)&Bl[wn + i * 16 + fr][fg * 8];
    }
#pragma unroll
    for (int i = 0; i < 4; ++i)
#pragma unroll
      for (int j = 0; j < 4; ++j) {
        acc[i][j] = __builtin_amdgcn_mfma_f32_16x16x32_f16(alo[i], bh[j], acc[i][j], 0, 0, 0);
        acc[i][j] = __builtin_amdgcn_mfma_f32_16x16x32_f16(ah[i], blo[j], acc[i][j], 0, 0, 0);
        acc[i][j] = __builtin_amdgcn_mfma_f32_16x16x32_f16(ah[i], bh[j], acc[i][j], 0, 0, 0);
      }
  }

  // epilogue: C/D layout col=lane&15, row=(lane>>4)*4+reg
#pragma unroll
  for (int i = 0; i < 4; ++i) {
#pragma unroll
    for (int j = 0; j < 4; ++j) {
      int col = n0 + wn + j * 16 + fr;
      if (col >= N) continue;
      float bb = bias ? bias[col] : 0.f;
#pragma unroll
      for (int r = 0; r < 4; ++r) {
        int m = m0 + wm + i * 16 + fg * 4 + r;
        if (m >= M) continue;
        C[(long)m * N + col] = acc[i][j][r] + bb;
      }
    }
  }
}

// ---------- actionness = sum over 20 classes (fp64 accumulate) ----------
__global__ __launch_bounds__(256) void actionness_k(const float* __restrict__ cas,
                                                    float* __restrict__ act) {
  int p = blockIdx.x * 256 + threadIdx.x;
  if (p >= 16 * 750) return;
  double s = 0.0;
#pragma unroll
  for (int c = 0; c < 20; ++c) s += (double)cas[(long)p * 20 + c];
  act[p] = (float)s;
}

// ---------- a2: two 1-channel k3 convs + relu ----------
__global__ __launch_bounds__(256) void a2_k(const float* __restrict__ act,
                                            const float* __restrict__ tf1w, const float* __restrict__ tf1b,
                                            const float* __restrict__ tf2w, const float* __restrict__ tf2b,
                                            float* __restrict__ a2out) {
  __shared__ float s0[752];
  __shared__ float s1[752];
  int b = blockIdx.x, tid = threadIdx.x;
  for (int i = tid; i < 752; i += 256) { s0[i] = 0.f; s1[i] = 0.f; }
  __syncthreads();
  for (int t = tid; t < 750; t += 256) s0[t + 1] = act[b * 750 + t];
  __syncthreads();
  float w0 = tf1w[0], w1 = tf1w[1], w2 = tf1w[2], bb1 = tf1b[0];
  for (int t = tid; t < 750; t += 256)
    s1[t + 1] = fmaxf(w0 * s0[t] + w1 * s0[t + 1] + w2 * s0[t + 2] + bb1, 0.f);
  __syncthreads();
  float u0 = tf2w[0], u1 = tf2w[1], u2 = tf2w[2], bb2 = tf2b[0];
  for (int t = tid; t < 750; t += 256)
    a2out[b * 750 + t] = fmaxf(u0 * s1[t] + u1 * s1[t + 1] + u2 * s1[t + 2] + bb2, 0.f);
}

// ---------- bitonic top-k (stable: key = score_bits<<32 | ~idx, descending) ----------
__global__ __launch_bounds__(256) void sort_topk_k(const float* __restrict__ scores,
                                                   int* __restrict__ out_idx, int K,
                                                   float* __restrict__ out_med,
                                                   float* __restrict__ out_mx) {
  __shared__ unsigned long long keys[1024];
  int b = blockIdx.x, tid = threadIdx.x;
  for (int i = tid; i < 1024; i += 256) {
    unsigned long long kv = 0ull;
    if (i < 750) {
      unsigned int bits = __float_as_uint(scores[b * 750 + i]);
      kv = ((unsigned long long)bits << 32) | (unsigned long long)(0xFFFFFFFFu - (unsigned)i);
    }
    keys[i] = kv;
  }
  __syncthreads();
  for (int k = 2; k <= 1024; k <<= 1) {
    for (int j = k >> 1; j > 0; j >>= 1) {
      for (int i = tid; i < 1024; i += 256) {
        int ixj = i ^ j;
        if (ixj > i) {
          unsigned long long a = keys[i], c = keys[ixj];
          bool sw = ((i & k) == 0) ? (a < c) : (a > c);   // overall descending
          if (sw) { keys[i] = c; keys[ixj] = a; }
        }
      }
      __syncthreads();
    }
  }
  for (int i = tid; i < K; i += 256)
    out_idx[b * K + i] = (int)(0xFFFFFFFFu - (unsigned int)(keys[i] & 0xFFFFFFFFull));
  if (tid == 0) {
    if (out_mx) out_mx[b] = __uint_as_float((unsigned int)(keys[0] >> 32));
    if (out_med) {
      float v1 = __uint_as_float((unsigned int)(keys[374] >> 32));
      float v2 = __uint_as_float((unsigned int)(keys[375] >> 32));
      out_med[b] = 0.5f * (v1 + v2);
    }
  }
}

// ---------- act_rev + binary morphology scores ----------
__global__ __launch_bounds__(256) void morph_k(const float* __restrict__ act,
                                               const float* __restrict__ med,
                                               const float* __restrict__ mxv,
                                               float* __restrict__ arev,
                                               float* __restrict__ hsa,
                                               float* __restrict__ hsb) {
  __shared__ float ab[756];   // ab[t+3] = abin[t], 3-wide zero margins
  int b = blockIdx.x, tid = threadIdx.x;
  float m = med[b], M = mxv[b];
  for (int i = tid; i < 756; i += 256) ab[i] = 0.f;
  __syncthreads();
  for (int t = tid; t < 750; t += 256) {
    float a = act[b * 750 + t];
    ab[t + 3] = (a > m) ? 1.f : 0.f;
    arev[b * 750 + t] = M - a;
  }
  __syncthreads();
  for (int t = tid; t < 750; t += 256) {
    float e3 = fminf(ab[t + 2], fminf(ab[t + 3], ab[t + 4]));                       // [t-1,t+1]
    float e6 = fminf(fminf(ab[t], ab[t + 1]),
                     fminf(fminf(ab[t + 2], ab[t + 3]), fminf(ab[t + 4], ab[t + 5]))); // [t-3,t+2]
    float d3 = fmaxf(ab[t + 2], fmaxf(ab[t + 3], ab[t + 4]));                       // [t-1,t+1]
    float d6 = fmaxf(fmaxf(ab[t + 1], ab[t + 2]),
                     fmaxf(fmaxf(ab[t + 3], ab[t + 4]), fmaxf(ab[t + 5], ab[t + 6]))); // [t-2,t+3]
    float a = act[b * 750 + t];
    hsa[b * 750 + t] = a * (e3 - e6);
    hsb[b * 750 + t] = a * (d6 - d3);
  }
}

// ---------- gather embedding rows by index ----------
__global__ __launch_bounds__(256) void gather_k(const float* __restrict__ emb,
                                                const int* __restrict__ idx,
                                                float* __restrict__ dst, int K) {
  int blk = blockIdx.x;
  int b = blk / K, i = blk - b * K;
  int t = idx[b * K + i];
  const float4* src = (const float4*)(emb + ((long)(b * 750 + t)) * 2048);
  float4* d = (float4*)(dst + (long)blk * 2048);
  for (int u = threadIdx.x; u < 512; u += 256) d[u] = src[u];
}

// ---------- video scores: per (b,c) mean of top-150 of cas[b,:,c] ----------
__global__ __launch_bounds__(256) void vtop_k(const float* __restrict__ cas,
                                              float* __restrict__ s) {
  __shared__ float v[1024];
  int b = blockIdx.x / 20, c = blockIdx.x - b * 20;
  int tid = threadIdx.x;
  for (int i = tid; i < 1024; i += 256)
    v[i] = (i < 750) ? cas[((long)(b * 750 + i)) * 20 + c] : -1.f;   // cas>=0, pads last
  __syncthreads();
  for (int k = 2; k <= 1024; k <<= 1) {
    for (int j = k >> 1; j > 0; j >>= 1) {
      for (int i = tid; i < 1024; i += 256) {
        int ixj = i ^ j;
        if (ixj > i) {
          float a = v[i], cc = v[ixj];
          bool sw = ((i & k) == 0) ? (a < cc) : (a > cc);
          if (sw) { v[i] = cc; v[ixj] = a; }
        }
      }
      __syncthreads();
    }
  }
  if (tid == 0) {
    float sum = 0.f;
    for (int i = 0; i < 150; ++i) sum += v[i];
    s[b * 20 + c] = sum / 150.f;
  }
}

__global__ __launch_bounds__(64) void softmax20_k(const float* __restrict__ s,
                                                  float* __restrict__ out) {
  int b = blockIdx.x;
  if (threadIdx.x != 0) return;
  float mx = -3.4e38f;
  for (int c = 0; c < 20; ++c) mx = fmaxf(mx, s[b * 20 + c]);
  float e[20]; float sum = 0.f;
  for (int c = 0; c < 20; ++c) { e[c] = expf(s[b * 20 + c] - mx); sum += e[c]; }
  for (int c = 0; c < 20; ++c) out[b * 20 + c] = e[c] / sum;
}

// ---------- attention scores + softmax: one wave per (call,b,h,qi) ----------
// q10 holds qkv projections for the 10 distinct inputs: [input][b*37+r][6144]
__global__ __launch_bounds__(64) void attn_scores_k(const float* __restrict__ q10,
                                                    int iA, int iB,
                                                    float* __restrict__ attnb) {
  int call = blockIdx.y;
  const float* q  = q10 + (long)(call ? iA : iB) * 592 * 6144;
  const float* kv = q10 + (long)(call ? iB : iA) * 592 * 6144;
  int x = blockIdx.x;
  int b = x / 148; int rem = x - b * 148; int h = rem / 37; int qi = rem - h * 37;
  int lane = threadIdx.x;
  const float scale = 0.04419417382415922f;   // 1/sqrt(512)
  const float* qp = q + ((long)(b * 37 + qi)) * 6144 + h * 512;
  float qr[8];
#pragma unroll
  for (int j = 0; j < 8; ++j) qr[j] = qp[lane + 64 * j] * scale;
  __shared__ float sc[37];
  for (int ki = 0; ki < 37; ++ki) {
    const float* kp = kv + ((long)(b * 37 + ki)) * 6144 + 2048 + h * 512;
    float d = 0.f;
#pragma unroll
    for (int j = 0; j < 8; ++j) d = fmaf(qr[j], kp[lane + 64 * j], d);
    for (int off = 32; off > 0; off >>= 1) d += __shfl_down(d, off, 64);
    if (lane == 0) sc[ki] = d;
  }
  __syncthreads();
  float v = (lane < 37) ? sc[lane] : -3.4e38f;
  float mx = v;
  for (int off = 32; off > 0; off >>= 1) mx = fmaxf(mx, __shfl_xor(mx, off, 64));
  float e = (lane < 37) ? expf(v - mx) : 0.f;
  float sum = e;
  for (int off = 32; off > 0; off >>= 1) sum += __shfl_xor(sum, off, 64);
  if (lane < 37)
    attnb[(((long)((call * 16 + b) * 4 + h)) * 37 + qi) * 37 + lane] = e / sum;
}

// ---------- attn @ V ----------
__global__ __launch_bounds__(256) void attn_v_k(const float* __restrict__ q10,
                                                int iA, int iB,
                                                const float* __restrict__ attnb,
                                                float* __restrict__ obuf) {
  int call = blockIdx.y;
  const float* kv = q10 + (long)(call ? iB : iA) * 592 * 6144;
  int x = blockIdx.x;
  int b = x / 37, qi = x - b * 37;
  int tid = threadIdx.x;
  __shared__ float at[4][37];
  if (tid < 148) {
    int h = tid / 37, ki = tid - h * 37;
    at[h][ki] = attnb[(((long)((call * 16 + b) * 4 + h)) * 37 + qi) * 37 + ki];
  }
  __syncthreads();
  int yoff = call ? 37 : 0;
  float* op = obuf + ((long)(b * 74 + yoff + qi)) * 2048;
#pragma unroll
  for (int i = 0; i < 8; ++i) {
    int c = tid + 256 * i;
    int h = c >> 9;
    float acc = 0.f;
#pragma unroll 1
    for (int ki = 0; ki < 37; ++ki)
      acc = fmaf(at[h][ki], kv[((long)(b * 37 + ki)) * 6144 + 4096 + c], acc);
    op[c] = acc;
  }
}

// ---------- l1 (74->10) + leaky + l2 (320->1) + sigmoid ----------
__global__ __launch_bounds__(320) void head_tail_k(const float* __restrict__ c2o,
                                                   const float* __restrict__ l1w,
                                                   const float* __restrict__ l1b,
                                                   const float* __restrict__ l2w,
                                                   const float* __restrict__ l2b,
                                                   float* __restrict__ out) {
  __shared__ float h[320];
  int b = blockIdx.x, tid = threadIdx.x;
  int c = tid / 10, j = tid - c * 10;
  float acc = l1b[j];
  for (int l = 0; l < 74; ++l)
    acc = fmaf(c2o[((long)(b * 74 + l)) * 32 + c], l1w[j * 74 + l], acc);
  acc = leaky_f(acc);
  h[c * 10 + j] = acc * l2w[c * 10 + j];
  __syncthreads();
  if (tid == 0) {
    float s = l2b[0];
    for (int i = 0; i < 320; ++i) s += h[i];
    out[b] = 1.f / (1.f + expf(-s));
  }
}

// ---------------------------------------------------------------------------
extern "C" void kernel_launch(void* const* d_in, const int* in_sizes, int n_in,
                              void* d_out, int out_size, void* d_ws, size_t ws_size,
                              hipStream_t stream) {
  const float* x       = (const float*)d_in[0];
  const float* w_embed = (const float*)d_in[1];
  const float* b_embed = (const float*)d_in[2];
  const float* w_cls   = (const float*)d_in[3];
  const float* tf1_w   = (const float*)d_in[4];
  const float* tf1_b   = (const float*)d_in[5];
  const float* tf2_w   = (const float*)d_in[6];
  const float* tf2_b   = (const float*)d_in[7];
  const float* in_w    = (const float*)d_in[8];
  const float* in_b    = (const float*)d_in[9];
  const float* out_w   = (const float*)d_in[10];
  const float* out_b   = (const float*)d_in[11];
  const float* c1_w    = (const float*)d_in[12];
  const float* c1_b    = (const float*)d_in[13];
  const float* c2_w    = (const float*)d_in[14];
  const float* c2_b    = (const float*)d_in[15];
  const float* l1_w    = (const float*)d_in[16];
  const float* l1_b    = (const float*)d_in[17];
  const float* l2_w    = (const float*)d_in[18];
  const float* l2_b    = (const float*)d_in[19];
  float* out = (float*)d_out;
  float* ws  = (float*)d_ws;

  // output offsets (floats)
  const long O_VS = 0, O_ACT = 320, O_A2 = 12320, O_CAS = 24320, O_RH = 264320;
  const long O_EA = 264512;
  const long O_EB = O_EA + 16L * 150 * 2048;
  const long O_HA = O_EB + 16L * 150 * 2048;
  const long O_HB = O_HA + 16L * 37 * 2048;

  // workspace layout (floats)
  long o = 0;
  float* emb   = ws + o; o += 12000L * 2048;      // 24,576,000
  float* wpkE  = ws + o; o += 3L * 2048 * 2048;   // 12,582,912
  // q10 (10 x 592 x 6144 = 36,372,480 floats) aliases emb+wpkE (37,158,912):
  // wpkE dies after the embed conv, emb dies after the gathers; the proj10
  // GEMM (which writes q10) launches after both. Stream order makes it safe.
  float* q10   = ws;
  float* wpk1  = ws + o; o += 3L * 128 * 2048;
  float* wpk2  = ws + o; o += 3L * 32 * 128;
  float* attnb = ws + o; o += 2L * 16 * 4 * 37 * 37;
  float* obuf  = ws + o; o += 16L * 74 * 2048;
  float* ybuf  = ws + o; o += 16L * 74 * 2048;
  float* c1o   = ws + o; o += 1184L * 128;
  float* c2o   = ws + o; o += 1184L * 32;
  float* arev  = ws + o; o += 12000;
  float* hsa   = ws + o; o += 12000;
  float* hsb   = ws + o; o += 12000;
  float* med   = ws + o; o += 16;
  float* mxv   = ws + o; o += 16;
  float* vsbuf = ws + o; o += 320;
  int* idxEA = (int*)(ws + o); o += 2400;
  int* idxEB = (int*)(ws + o); o += 2400;
  int* idxHA = (int*)(ws + o); o += 592;
  int* idxHB = (int*)(ws + o); o += 592;
  (void)ws_size; (void)in_sizes; (void)n_in; (void)out_size;

  // 1. pack conv weights (n,k,tap) -> (tap,n,k)
  pack_w_k<<<(12582912 + 255) / 256, 256, 0, stream>>>(w_embed, wpkE, 2048, 2048, 3);
  pack_w_k<<<(786432 + 255) / 256, 256, 0, stream>>>(c1_w, wpk1, 128, 2048, 3);
  pack_w_k<<<(12288 + 255) / 256, 256, 0, stream>>>(c2_w, wpk2, 32, 128, 3);

  // 2. embed conv (k3, 2048->2048) + relu — fp64 tile accumulation
  //    (selection-critical: do NOT lower precision here)
  gemm64_k<1><<<dim3(32, 188), 256, 0, stream>>>(x, wpkE, b_embed, emb,
      12000, 2048, 2048, 3, -1, 750, 1536000L, 750, 1536000L, 1);

  // 3. cas (1x1, 2048->20) + relu — fp64 tile accumulation
  gemm32_k<1><<<dim3(1, 375), 256, 0, stream>>>(emb, w_cls, nullptr, out + O_CAS,
      12000, 20, 2048, 1, 0, 750, 1536000L, 750, 15000L, 1);

  // 4. actionness, a2
  actionness_k<<<47, 256, 0, stream>>>(out + O_CAS, out + O_ACT);
  a2_k<<<16, 256, 0, stream>>>(out + O_ACT, tf1_w, tf1_b, tf2_w, tf2_b, out + O_A2);

  // 5. video scores
  vtop_k<<<320, 256, 0, stream>>>(out + O_CAS, vsbuf);
  softmax20_k<<<16, 64, 0, stream>>>(vsbuf, out + O_VS);

  // 6. selections
  sort_topk_k<<<16, 256, 0, stream>>>(out + O_ACT, idxEA, 150, med, mxv);
  morph_k<<<16, 256, 0, stream>>>(out + O_ACT, med, mxv, arev, hsa, hsb);
  sort_topk_k<<<16, 256, 0, stream>>>(arev, idxEB, 150, nullptr, nullptr);
  sort_topk_k<<<16, 256, 0, stream>>>(hsa, idxHA, 37, nullptr, nullptr);
  sort_topk_k<<<16, 256, 0, stream>>>(hsb, idxHB, 37, nullptr, nullptr);

  gather_k<<<2400, 256, 0, stream>>>(emb, idxEA, out + O_EA, 150);
  gather_k<<<2400, 256, 0, stream>>>(emb, idxEB, out + O_EB, 150);
  gather_k<<<592, 256, 0, stream>>>(emb, idxHA, out + O_HA, 37);
  gather_k<<<592, 256, 0, stream>>>(emb, idxHB, out + O_HB, 37);

  // 7. qkv projection for ALL 10 distinct head inputs in one MFMA GEMM:
  //    M = 10*592 = 5920, N = 6144, K = 2048  (emb/wpkE are dead now)
  gemmx3_k<1><<<dim3(48, 47), 256, 0, stream>>>(out, in_w, in_b, q10,
      5920, 6144, 2048, O_EA, O_EB, O_HA, O_HB);

  // 8. relational heads: input indices into q10
  //    0..3 = ea0..3, 4..7 = eb0..3, 8 = hA, 9 = hB
  const int pidx[12][2] = {
    {1, 8},  // re_a_0h
    {3, 2},  // re_a_02
    {0, 3},  // re_a_03
    {5, 9},  // re_b_0h
    {7, 6},  // re_b_02
    {4, 7},  // re_b_03
    {9, 8},  // re_ab_hh
    {3, 9},  // re_ab_3h
    {8, 7},  // re_ab_h3
    {3, 7},  // re_ab_33
    {6, 3},  // re_ab_32
    {2, 7},  // re_ab_23
  };

  for (int i = 0; i < 12; ++i) {
    int iA = pidx[i][0], iB = pidx[i][1];
    attn_scores_k<<<dim3(2368, 2), 64, 0, stream>>>(q10, iA, iB, attnb);
    attn_v_k<<<dim3(592, 2), 256, 0, stream>>>(q10, iA, iB, attnb, obuf);
    // out-proj (1184 x 2048 x 2048) on matrix cores
    gemmx3_k<0><<<dim3(16, 10), 256, 0, stream>>>(obuf, out_w, out_b, ybuf,
        1184, 2048, 2048, 0, 0, 0, 0);
    gemm32_k<0><<<dim3(4, 37), 256, 0, stream>>>(ybuf, wpk1, c1_b, c1o,
        1184, 128, 2048, 3, -1, 74, 74L * 2048, 74, 74L * 128, 2);
    gemm32_k<0><<<dim3(1, 37), 256, 0, stream>>>(c1o, wpk2, c2_b, c2o,
        1184, 32, 128, 3, -1, 74, 74L * 128, 74, 74L * 32, 2);
    head_tail_k<<<16, 320, 0, stream>>>(c2o, l1_w, l1_b, l2_w, l2_b, out + O_RH + 16L * i);
  }
}

// Round 2
// 8215.394 us; speedup vs baseline: 2.1378x; 1.3992x over previous
//
#include <hip/hip_runtime.h>

// ---------------------------------------------------------------------------
// CoLA forward on MI355X — round 4: embed conv (the 5.5ms, 48%-of-runtime
// dispatch) moved to matrix cores via f16 hi/lo x3 emulation with WINDOWED
// fp32 accumulation (zero MFMA acc every 24 K-chunks, drain to fp32 master)
// to keep numerical error (~2.5e-6) below the fp32 reference's own noise
// (~7e-6) so top-k/median selection boundaries are preserved.
// cas (-> actionness -> selections) stays on the exact fp64-accum path.
// ---------------------------------------------------------------------------

static __device__ __forceinline__ float leaky_f(float x) { return x >= 0.f ? x : 0.2f * x; }

typedef _Float16 f16;
typedef f16 f16x4 __attribute__((ext_vector_type(4)));
typedef f16 f16x8 __attribute__((ext_vector_type(8)));
typedef float f32x4 __attribute__((ext_vector_type(4)));

// ---------- pack (N,KC,taps) -> (taps,N,KC) ----------
__global__ __launch_bounds__(256) void pack_w_k(const float* __restrict__ src,
                                                float* __restrict__ dst,
                                                int N, int KC, int taps) {
  long total = (long)N * KC * taps;
  long i = (long)blockIdx.x * 256 + threadIdx.x;
  if (i >= total) return;
  long nk = (long)N * KC;
  int tap = (int)(i / nk);
  long rem = i - (long)tap * nk;
  int n = (int)(rem / KC);
  int k = (int)(rem - (long)n * KC);
  dst[i] = src[((long)n * KC + k) * taps + tap];
}

// ---------- pack + f16 hi/lo split: (N,KC,taps) f32 -> (taps,N,KC) f16 x2 ----------
__global__ __launch_bounds__(256) void pack_split_w_k(const float* __restrict__ src,
                                                      f16* __restrict__ dh,
                                                      f16* __restrict__ dl,
                                                      int N, int KC, int taps) {
  long total = (long)N * KC * taps;
  long i = (long)blockIdx.x * 256 + threadIdx.x;
  if (i >= total) return;
  long nk = (long)N * KC;
  int tap = (int)(i / nk);
  long rem = i - (long)tap * nk;
  int n = (int)(rem / KC);
  int k = (int)(rem - (long)n * KC);
  float v = src[((long)n * KC + k) * taps + tap];
  f16 h = (f16)v;
  dh[i] = h;
  dl[i] = (f16)(v - (float)h);
}

// ---------------------------------------------------------------------------
// embed conv on MFMA: emb[m][n] = relu(sum_{tap,c} x[m+tap-1][c]*w[tap][n][c] + b[n])
// M=12000 (16 batches x 750, zero-pad at batch edges), N=2048, C=2048, taps=3.
// A (x) is fp32, split to f16 hi/lo in-kernel; B (w) pre-split f16 hi/lo.
// 3 MFMAs per fragment pair (al*bh + ah*bl + ah*bh), fp32 accumulator zeroed
// every 24 K-chunks and drained into fp32 master (bounds rounding error).
// 128x128 tile, 4 waves of 64x64.
// ---------------------------------------------------------------------------
__global__ __launch_bounds__(256) void emb_mfma_k(
    const float* __restrict__ x, const f16* __restrict__ wh,
    const f16* __restrict__ wl, const float* __restrict__ bias,
    float* __restrict__ emb) {
  __shared__ f16 Ah[128][40];
  __shared__ f16 Al[128][40];
  __shared__ f16 Bh[128][40];
  __shared__ f16 Bl[128][40];
  int t = threadIdx.x;
  int n0 = blockIdx.x * 128, m0 = blockIdx.y * 128;

  // staging: thread t stages row sr = t>>1, halves [sc, sc+16)
  int sr = t >> 1;
  int sc = (t & 1) << 4;
  int am = m0 + sr;               // output row this thread stages for A
  int at = am % 750;              // row-in-batch (am < 12032, guarded below)

  int lane = t & 63, wv = t >> 6;
  int wm = (wv >> 1) * 64, wn = (wv & 1) * 64;
  int fr = lane & 15, fg = lane >> 4;

  f32x4 acc[4][4], mst[4][4];
#pragma unroll
  for (int i = 0; i < 4; ++i)
#pragma unroll
    for (int j = 0; j < 4; ++j) { acc[i][j] = (f32x4)(0.f); mst[i][j] = (f32x4)(0.f); }

  // 192 K-chunks of 32 (3 taps x 64 chunks), in 8 windows of 24
  for (int w8 = 0; w8 < 8; ++w8) {
#pragma unroll 1
    for (int c24 = 0; c24 < 24; ++c24) {
      int kt = w8 * 24 + c24;
      int tap = kt >> 6;
      int k0 = (kt & 63) << 5;

      // ---- A global load (fp32, with conv shift + batch-edge zeroing) ----
      int rr = at + tap - 1;
      bool av = (am < 12000) && (rr >= 0) && (rr < 750);
      const float* ap = x + (long)(am + tap - 1) * 2048 + k0 + sc;
      float4 a4[4];
#pragma unroll
      for (int q = 0; q < 4; ++q)
        a4[q] = av ? *(const float4*)(ap + q * 4) : make_float4(0.f, 0.f, 0.f, 0.f);

      // ---- B global load (pre-split f16 hi/lo) ----
      const f16* bph = wh + ((long)tap * 2048 + (n0 + sr)) * 2048 + k0 + sc;
      const f16* bpl = wl + ((long)tap * 2048 + (n0 + sr)) * 2048 + k0 + sc;
      f16x8 bh0 = *(const f16x8*)bph;
      f16x8 bh1 = *(const f16x8*)(bph + 8);
      f16x8 bl0 = *(const f16x8*)bpl;
      f16x8 bl1 = *(const f16x8*)(bpl + 8);

      __syncthreads();   // previous chunk's frag reads done

      // ---- split A, store all tiles ----
#pragma unroll
      for (int q = 0; q < 4; ++q) {
        float xs[4] = {a4[q].x, a4[q].y, a4[q].z, a4[q].w};
        f16x4 h4, l4;
#pragma unroll
        for (int e = 0; e < 4; ++e) {
          f16 hh = (f16)xs[e];
          h4[e] = hh;
          l4[e] = (f16)(xs[e] - (float)hh);
        }
        *(f16x4*)&Ah[sr][sc + q * 4] = h4;
        *(f16x4*)&Al[sr][sc + q * 4] = l4;
      }
      *(f16x8*)&Bh[sr][sc] = bh0;
      *(f16x8*)&Bh[sr][sc + 8] = bh1;
      *(f16x8*)&Bl[sr][sc] = bl0;
      *(f16x8*)&Bl[sr][sc + 8] = bl1;
      __syncthreads();

      // ---- fragments + 48 MFMA ----
      f16x8 fah[4], fal[4], fbh[4], fbl[4];
#pragma unroll
      for (int i = 0; i < 4; ++i) {
        fah[i] = *(const f16x8*)&Ah[wm + i * 16 + fr][fg * 8];
        fal[i] = *(const f16x8*)&Al[wm + i * 16 + fr][fg * 8];
        fbh[i] = *(const f16x8*)&Bh[wn + i * 16 + fr][fg * 8];
        fbl[i] = *(const f16x8*)&Bl[wn + i * 16 + fr][fg * 8];
      }
#pragma unroll
      for (int i = 0; i < 4; ++i)
#pragma unroll
        for (int j = 0; j < 4; ++j) {
          acc[i][j] = __builtin_amdgcn_mfma_f32_16x16x32_f16(fal[i], fbh[j], acc[i][j], 0, 0, 0);
          acc[i][j] = __builtin_amdgcn_mfma_f32_16x16x32_f16(fah[i], fbl[j], acc[i][j], 0, 0, 0);
          acc[i][j] = __builtin_amdgcn_mfma_f32_16x16x32_f16(fah[i], fbh[j], acc[i][j], 0, 0, 0);
        }
    }
    // ---- window drain: bound fp32 accumulation error ----
#pragma unroll
    for (int i = 0; i < 4; ++i)
#pragma unroll
      for (int j = 0; j < 4; ++j) { mst[i][j] += acc[i][j]; acc[i][j] = (f32x4)(0.f); }
  }

  // epilogue: C/D layout col=lane&15, row=(lane>>4)*4+reg
#pragma unroll
  for (int i = 0; i < 4; ++i) {
#pragma unroll
    for (int j = 0; j < 4; ++j) {
      int col = n0 + wn + j * 16 + fr;           // always < 2048
      float bb = bias[col];
#pragma unroll
      for (int r = 0; r < 4; ++r) {
        int m = m0 + wm + i * 16 + fg * 4 + r;
        if (m < 12000)
          emb[(long)m * 2048 + col] = fmaxf(mst[i][j][r] + bb, 0.f);
      }
    }
  }
}

// ---------- 32x32 fp32 GEMM variant (small N), K-tile 32 ----------
template <int DACC>
__global__ __launch_bounds__(256) void gemm32_k(
    const float* __restrict__ A, const float* __restrict__ Bw,
    const float* __restrict__ bias, float* __restrict__ C,
    int M, int N, int KC, int taps, int shift_base,
    int a_grp, long a_bstride, int c_grp, long c_bstride, int act) {
  __shared__ __align__(16) float As[32][36];
  __shared__ __align__(16) float Bs[32][36];
  int tid = threadIdx.x;
  int n0 = blockIdx.x * 32, m0 = blockIdx.y * 32;
  int tx = tid & 15, ty = tid >> 4;
  int row_l = tid >> 3;          // 0..31
  int kq = (tid & 7) << 2;       // 0..28
  float accf[2][2] = {{0.f}};
  double accd[2][2];
  if (DACC) { accd[0][0] = accd[0][1] = accd[1][0] = accd[1][1] = 0.0; }
  int tpt = KC >> 5;
  int nkt = tpt * taps;
  int am = m0 + row_l;
  int agrp = 0, ar = 0;
  if (am < M) { agrp = am / a_grp; ar = am - agrp * a_grp; }
  int bn = n0 + row_l;
  for (int kt = 0; kt < nkt; ++kt) {
    int tap = kt / tpt;
    int k0 = (kt - tap * tpt) << 5;
    float4 av = make_float4(0.f, 0.f, 0.f, 0.f);
    float4 bv = make_float4(0.f, 0.f, 0.f, 0.f);
    if (am < M) {
      int rr = ar + tap + shift_base;
      if (rr >= 0 && rr < a_grp)
        av = *(const float4*)(A + (long)agrp * a_bstride + (long)rr * KC + (k0 + kq));
    }
    if (bn < N)
      bv = *(const float4*)(Bw + ((long)tap * N + bn) * KC + (k0 + kq));
    __syncthreads();
    As[kq + 0][row_l] = av.x; As[kq + 1][row_l] = av.y;
    As[kq + 2][row_l] = av.z; As[kq + 3][row_l] = av.w;
    Bs[kq + 0][row_l] = bv.x; Bs[kq + 1][row_l] = bv.y;
    Bs[kq + 2][row_l] = bv.z; Bs[kq + 3][row_l] = bv.w;
    __syncthreads();
    float tile[2][2] = {{0.f, 0.f}, {0.f, 0.f}};
#pragma unroll
    for (int k = 0; k < 32; ++k) {
      float2 a2 = *(const float2*)&As[k][ty << 1];
      float2 b2 = *(const float2*)&Bs[k][tx << 1];
      if (DACC) {
        tile[0][0] = fmaf(a2.x, b2.x, tile[0][0]);
        tile[0][1] = fmaf(a2.x, b2.y, tile[0][1]);
        tile[1][0] = fmaf(a2.y, b2.x, tile[1][0]);
        tile[1][1] = fmaf(a2.y, b2.y, tile[1][1]);
      } else {
        accf[0][0] = fmaf(a2.x, b2.x, accf[0][0]);
        accf[0][1] = fmaf(a2.x, b2.y, accf[0][1]);
        accf[1][0] = fmaf(a2.y, b2.x, accf[1][0]);
        accf[1][1] = fmaf(a2.y, b2.y, accf[1][1]);
      }
    }
    if (DACC) {
      accd[0][0] += (double)tile[0][0]; accd[0][1] += (double)tile[0][1];
      accd[1][0] += (double)tile[1][0]; accd[1][1] += (double)tile[1][1];
    }
  }
#pragma unroll
  for (int i = 0; i < 2; ++i) {
    int m = m0 + (ty << 1) + i;
    if (m >= M) continue;
    int grp = m / c_grp, r = m - grp * c_grp;
    float* crow = C + (long)grp * c_bstride + (long)r * N;
#pragma unroll
    for (int j = 0; j < 2; ++j) {
      int n = n0 + (tx << 1) + j;
      if (n >= N) continue;
      float v = DACC ? (float)accd[i][j] : accf[i][j];
      if (bias) v += bias[n];
      if (act == 1) v = fmaxf(v, 0.f);
      else if (act == 2) v = leaky_f(v);
      crow[n] = v;
    }
  }
}

// ---------------------------------------------------------------------------
// MFMA f16x3 GEMM: C[M][N] = A[M][K] * Bw[N][K]^T + bias, fp32-faithful via
// hi/lo f16 split (3 mfma per 16x16x32 tile). 128x128 tile, 4 waves, each
// wave does a 64x64 sub-tile (4x4 frags). K multiple of 32.
// AMODE 0: A rows contiguous (stride K).
// AMODE 1: A rows are the 10 distinct head inputs living in `out`.
// ---------------------------------------------------------------------------
template <int AMODE>
__global__ __launch_bounds__(256) void gemmx3_k(
    const float* __restrict__ Abase, const float* __restrict__ Bw,
    const float* __restrict__ bias, float* __restrict__ C,
    int M, int N, int K,
    long oEA, long oEB, long oHA, long oHB) {
  __shared__ _Float16 Ah[128][40];
  __shared__ _Float16 Al[128][40];
  __shared__ _Float16 Bh[128][40];
  __shared__ _Float16 Bl[128][40];
  int t = threadIdx.x;
  int m0 = blockIdx.y * 128, n0 = blockIdx.x * 128;

  int lr = t >> 3;
  int lq = t & 7;
  const float* arow[4];
  const float* brow[4];
#pragma unroll
  for (int p = 0; p < 4; ++p) {
    int m = m0 + p * 32 + lr;
    if (m < M) {
      if (AMODE == 0) {
        arow[p] = Abase + (long)m * K;
      } else {
        int inp = m / 592;
        int rem = m - inp * 592;
        int b = rem / 37;
        int r = rem - b * 37;
        long base, bstr;
        if (inp < 8) { base = (inp < 4 ? oEA : oEB) + (long)(inp & 3) * (37L * 2048); bstr = 150L * 2048; }
        else         { base = (inp == 8) ? oHA : oHB; bstr = 37L * 2048; }
        arow[p] = Abase + base + (long)b * bstr + (long)r * 2048;
      }
    } else arow[p] = nullptr;
    int n = n0 + p * 32 + lr;
    brow[p] = (n < N) ? (Bw + (long)n * K) : nullptr;
  }

  int lane = t & 63;
  int wv = t >> 6;
  int wm = (wv >> 1) * 64, wn = (wv & 1) * 64;
  int fr = lane & 15, fg = lane >> 4;

  f32x4 acc[4][4];
#pragma unroll
  for (int i = 0; i < 4; ++i)
#pragma unroll
    for (int j = 0; j < 4; ++j) acc[i][j] = (f32x4)(0.f);

  int nkt = K >> 5;
  for (int kt = 0; kt < nkt; ++kt) {
    int k0 = kt << 5;
    float4 av[4], bv[4];
#pragma unroll
    for (int p = 0; p < 4; ++p) {
      av[p] = arow[p] ? *(const float4*)(arow[p] + k0 + lq * 4) : make_float4(0.f, 0.f, 0.f, 0.f);
      bv[p] = brow[p] ? *(const float4*)(brow[p] + k0 + lq * 4) : make_float4(0.f, 0.f, 0.f, 0.f);
    }
    __syncthreads();
#pragma unroll
    for (int p = 0; p < 4; ++p) {
      int row = p * 32 + lr;
      float xs[4] = {av[p].x, av[p].y, av[p].z, av[p].w};
      f16x4 h, l;
#pragma unroll
      for (int e = 0; e < 4; ++e) {
        f16 hh = (f16)xs[e];
        h[e] = hh;
        l[e] = (f16)(xs[e] - (float)hh);
      }
      *(f16x4*)&Ah[row][lq * 4] = h;
      *(f16x4*)&Al[row][lq * 4] = l;
      float ys[4] = {bv[p].x, bv[p].y, bv[p].z, bv[p].w};
#pragma unroll
      for (int e = 0; e < 4; ++e) {
        f16 hh = (f16)ys[e];
        h[e] = hh;
        l[e] = (f16)(ys[e] - (float)hh);
      }
      *(f16x4*)&Bh[row][lq * 4] = h;
      *(f16x4*)&Bl[row][lq * 4] = l;
    }
    __syncthreads();
    f16x8 ah[4], alo[4], bh[4], blo[4];
#pragma unroll
    for (int i = 0; i < 4; ++i) {
      ah[i]  = *(const f16x8*)&Ah[wm + i * 16 + fr][fg * 8];
      alo[i] = *(const f16x8*)&Al[wm + i * 16 + fr][fg * 8];
      bh[i]  = *(const f16x8*)&Bh[wn + i * 16 + fr][fg * 8];
      blo[i] = *(const f16x8*)&Bl[wn + i * 16 + fr][fg * 8];
    }
#pragma unroll
    for (int i = 0; i < 4; ++i)
#pragma unroll
      for (int j = 0; j < 4; ++j) {
        acc[i][j] = __builtin_amdgcn_mfma_f32_16x16x32_f16(alo[i], bh[j], acc[i][j], 0, 0, 0);
        acc[i][j] = __builtin_amdgcn_mfma_f32_16x16x32_f16(ah[i], blo[j], acc[i][j], 0, 0, 0);
        acc[i][j] = __builtin_amdgcn_mfma_f32_16x16x32_f16(ah[i], bh[j], acc[i][j], 0, 0, 0);
      }
  }

#pragma unroll
  for (int i = 0; i < 4; ++i) {
#pragma unroll
    for (int j = 0; j < 4; ++j) {
      int col = n0 + wn + j * 16 + fr;
      if (col >= N) continue;
      float bb = bias ? bias[col] : 0.f;
#pragma unroll
      for (int r = 0; r < 4; ++r) {
        int m = m0 + wm + i * 16 + fg * 4 + r;
        if (m >= M) continue;
        C[(long)m * N + col] = acc[i][j][r] + bb;
      }
    }
  }
}

// ---------- actionness = sum over 20 classes (fp64 accumulate) ----------
__global__ __launch_bounds__(256) void actionness_k(const float* __restrict__ cas,
                                                    float* __restrict__ act) {
  int p = blockIdx.x * 256 + threadIdx.x;
  if (p >= 16 * 750) return;
  double s = 0.0;
#pragma unroll
  for (int c = 0; c < 20; ++c) s += (double)cas[(long)p * 20 + c];
  act[p] = (float)s;
}

// ---------- a2: two 1-channel k3 convs + relu ----------
__global__ __launch_bounds__(256) void a2_k(const float* __restrict__ act,
                                            const float* __restrict__ tf1w, const float* __restrict__ tf1b,
                                            const float* __restrict__ tf2w, const float* __restrict__ tf2b,
                                            float* __restrict__ a2out) {
  __shared__ float s0[752];
  __shared__ float s1[752];
  int b = blockIdx.x, tid = threadIdx.x;
  for (int i = tid; i < 752; i += 256) { s0[i] = 0.f; s1[i] = 0.f; }
  __syncthreads();
  for (int t = tid; t < 750; t += 256) s0[t + 1] = act[b * 750 + t];
  __syncthreads();
  float w0 = tf1w[0], w1 = tf1w[1], w2 = tf1w[2], bb1 = tf1b[0];
  for (int t = tid; t < 750; t += 256)
    s1[t + 1] = fmaxf(w0 * s0[t] + w1 * s0[t + 1] + w2 * s0[t + 2] + bb1, 0.f);
  __syncthreads();
  float u0 = tf2w[0], u1 = tf2w[1], u2 = tf2w[2], bb2 = tf2b[0];
  for (int t = tid; t < 750; t += 256)
    a2out[b * 750 + t] = fmaxf(u0 * s1[t] + u1 * s1[t + 1] + u2 * s1[t + 2] + bb2, 0.f);
}

// ---------- bitonic top-k (stable: key = score_bits<<32 | ~idx, descending) ----------
__global__ __launch_bounds__(256) void sort_topk_k(const float* __restrict__ scores,
                                                   int* __restrict__ out_idx, int K,
                                                   float* __restrict__ out_med,
                                                   float* __restrict__ out_mx) {
  __shared__ unsigned long long keys[1024];
  int b = blockIdx.x, tid = threadIdx.x;
  for (int i = tid; i < 1024; i += 256) {
    unsigned long long kv = 0ull;
    if (i < 750) {
      unsigned int bits = __float_as_uint(scores[b * 750 + i]);
      kv = ((unsigned long long)bits << 32) | (unsigned long long)(0xFFFFFFFFu - (unsigned)i);
    }
    keys[i] = kv;
  }
  __syncthreads();
  for (int k = 2; k <= 1024; k <<= 1) {
    for (int j = k >> 1; j > 0; j >>= 1) {
      for (int i = tid; i < 1024; i += 256) {
        int ixj = i ^ j;
        if (ixj > i) {
          unsigned long long a = keys[i], c = keys[ixj];
          bool sw = ((i & k) == 0) ? (a < c) : (a > c);   // overall descending
          if (sw) { keys[i] = c; keys[ixj] = a; }
        }
      }
      __syncthreads();
    }
  }
  for (int i = tid; i < K; i += 256)
    out_idx[b * K + i] = (int)(0xFFFFFFFFu - (unsigned int)(keys[i] & 0xFFFFFFFFull));
  if (tid == 0) {
    if (out_mx) out_mx[b] = __uint_as_float((unsigned int)(keys[0] >> 32));
    if (out_med) {
      float v1 = __uint_as_float((unsigned int)(keys[374] >> 32));
      float v2 = __uint_as_float((unsigned int)(keys[375] >> 32));
      out_med[b] = 0.5f * (v1 + v2);
    }
  }
}

// ---------- act_rev + binary morphology scores ----------
__global__ __launch_bounds__(256) void morph_k(const float* __restrict__ act,
                                               const float* __restrict__ med,
                                               const float* __restrict__ mxv,
                                               float* __restrict__ arev,
                                               float* __restrict__ hsa,
                                               float* __restrict__ hsb) {
  __shared__ float ab[756];   // ab[t+3] = abin[t], 3-wide zero margins
  int b = blockIdx.x, tid = threadIdx.x;
  float m = med[b], M = mxv[b];
  for (int i = tid; i < 756; i += 256) ab[i] = 0.f;
  __syncthreads();
  for (int t = tid; t < 750; t += 256) {
    float a = act[b * 750 + t];
    ab[t + 3] = (a > m) ? 1.f : 0.f;
    arev[b * 750 + t] = M - a;
  }
  __syncthreads();
  for (int t = tid; t < 750; t += 256) {
    float e3 = fminf(ab[t + 2], fminf(ab[t + 3], ab[t + 4]));
    float e6 = fminf(fminf(ab[t], ab[t + 1]),
                     fminf(fminf(ab[t + 2], ab[t + 3]), fminf(ab[t + 4], ab[t + 5])));
    float d3 = fmaxf(ab[t + 2], fmaxf(ab[t + 3], ab[t + 4]));
    float d6 = fmaxf(fmaxf(ab[t + 1], ab[t + 2]),
                     fmaxf(fmaxf(ab[t + 3], ab[t + 4]), fmaxf(ab[t + 5], ab[t + 6])));
    float a = act[b * 750 + t];
    hsa[b * 750 + t] = a * (e3 - e6);
    hsb[b * 750 + t] = a * (d6 - d3);
  }
}

// ---------- gather embedding rows by index ----------
__global__ __launch_bounds__(256) void gather_k(const float* __restrict__ emb,
                                                const int* __restrict__ idx,
                                                float* __restrict__ dst, int K) {
  int blk = blockIdx.x;
  int b = blk / K, i = blk - b * K;
  int t = idx[b * K + i];
  const float4* src = (const float4*)(emb + ((long)(b * 750 + t)) * 2048);
  float4* d = (float4*)(dst + (long)blk * 2048);
  for (int u = threadIdx.x; u < 512; u += 256) d[u] = src[u];
}

// ---------- video scores: per (b,c) mean of top-150 of cas[b,:,c] ----------
__global__ __launch_bounds__(256) void vtop_k(const float* __restrict__ cas,
                                              float* __restrict__ s) {
  __shared__ float v[1024];
  int b = blockIdx.x / 20, c = blockIdx.x - b * 20;
  int tid = threadIdx.x;
  for (int i = tid; i < 1024; i += 256)
    v[i] = (i < 750) ? cas[((long)(b * 750 + i)) * 20 + c] : -1.f;
  __syncthreads();
  for (int k = 2; k <= 1024; k <<= 1) {
    for (int j = k >> 1; j > 0; j >>= 1) {
      for (int i = tid; i < 1024; i += 256) {
        int ixj = i ^ j;
        if (ixj > i) {
          float a = v[i], cc = v[ixj];
          bool sw = ((i & k) == 0) ? (a < cc) : (a > cc);
          if (sw) { v[i] = cc; v[ixj] = a; }
        }
      }
      __syncthreads();
    }
  }
  if (tid == 0) {
    float sum = 0.f;
    for (int i = 0; i < 150; ++i) sum += v[i];
    s[b * 20 + c] = sum / 150.f;
  }
}

__global__ __launch_bounds__(64) void softmax20_k(const float* __restrict__ s,
                                                  float* __restrict__ out) {
  int b = blockIdx.x;
  if (threadIdx.x != 0) return;
  float mx = -3.4e38f;
  for (int c = 0; c < 20; ++c) mx = fmaxf(mx, s[b * 20 + c]);
  float e[20]; float sum = 0.f;
  for (int c = 0; c < 20; ++c) { e[c] = expf(s[b * 20 + c] - mx); sum += e[c]; }
  for (int c = 0; c < 20; ++c) out[b * 20 + c] = e[c] / sum;
}

// ---------- attention scores + softmax: one wave per (call,b,h,qi) ----------
__global__ __launch_bounds__(64) void attn_scores_k(const float* __restrict__ q10,
                                                    int iA, int iB,
                                                    float* __restrict__ attnb) {
  int call = blockIdx.y;
  const float* q  = q10 + (long)(call ? iA : iB) * 592 * 6144;
  const float* kv = q10 + (long)(call ? iB : iA) * 592 * 6144;
  int x = blockIdx.x;
  int b = x / 148; int rem = x - b * 148; int h = rem / 37; int qi = rem - h * 37;
  int lane = threadIdx.x;
  const float scale = 0.04419417382415922f;   // 1/sqrt(512)
  const float* qp = q + ((long)(b * 37 + qi)) * 6144 + h * 512;
  float qr[8];
#pragma unroll
  for (int j = 0; j < 8; ++j) qr[j] = qp[lane + 64 * j] * scale;
  __shared__ float sc[37];
  for (int ki = 0; ki < 37; ++ki) {
    const float* kp = kv + ((long)(b * 37 + ki)) * 6144 + 2048 + h * 512;
    float d = 0.f;
#pragma unroll
    for (int j = 0; j < 8; ++j) d = fmaf(qr[j], kp[lane + 64 * j], d);
    for (int off = 32; off > 0; off >>= 1) d += __shfl_down(d, off, 64);
    if (lane == 0) sc[ki] = d;
  }
  __syncthreads();
  float v = (lane < 37) ? sc[lane] : -3.4e38f;
  float mx = v;
  for (int off = 32; off > 0; off >>= 1) mx = fmaxf(mx, __shfl_xor(mx, off, 64));
  float e = (lane < 37) ? expf(v - mx) : 0.f;
  float sum = e;
  for (int off = 32; off > 0; off >>= 1) sum += __shfl_xor(sum, off, 64);
  if (lane < 37)
    attnb[(((long)((call * 16 + b) * 4 + h)) * 37 + qi) * 37 + lane] = e / sum;
}

// ---------- attn @ V ----------
__global__ __launch_bounds__(256) void attn_v_k(const float* __restrict__ q10,
                                                int iA, int iB,
                                                const float* __restrict__ attnb,
                                                float* __restrict__ obuf) {
  int call = blockIdx.y;
  const float* kv = q10 + (long)(call ? iB : iA) * 592 * 6144;
  int x = blockIdx.x;
  int b = x / 37, qi = x - b * 37;
  int tid = threadIdx.x;
  __shared__ float at[4][37];
  if (tid < 148) {
    int h = tid / 37, ki = tid - h * 37;
    at[h][ki] = attnb[(((long)((call * 16 + b) * 4 + h)) * 37 + qi) * 37 + ki];
  }
  __syncthreads();
  int yoff = call ? 37 : 0;
  float* op = obuf + ((long)(b * 74 + yoff + qi)) * 2048;
#pragma unroll
  for (int i = 0; i < 8; ++i) {
    int c = tid + 256 * i;
    int h = c >> 9;
    float acc = 0.f;
#pragma unroll 1
    for (int ki = 0; ki < 37; ++ki)
      acc = fmaf(at[h][ki], kv[((long)(b * 37 + ki)) * 6144 + 4096 + c], acc);
    op[c] = acc;
  }
}

// ---------- l1 (74->10) + leaky + l2 (320->1) + sigmoid ----------
__global__ __launch_bounds__(320) void head_tail_k(const float* __restrict__ c2o,
                                                   const float* __restrict__ l1w,
                                                   const float* __restrict__ l1b,
                                                   const float* __restrict__ l2w,
                                                   const float* __restrict__ l2b,
                                                   float* __restrict__ out) {
  __shared__ float h[320];
  int b = blockIdx.x, tid = threadIdx.x;
  int c = tid / 10, j = tid - c * 10;
  float acc = l1b[j];
  for (int l = 0; l < 74; ++l)
    acc = fmaf(c2o[((long)(b * 74 + l)) * 32 + c], l1w[j * 74 + l], acc);
  acc = leaky_f(acc);
  h[c * 10 + j] = acc * l2w[c * 10 + j];
  __syncthreads();
  if (tid == 0) {
    float s = l2b[0];
    for (int i = 0; i < 320; ++i) s += h[i];
    out[b] = 1.f / (1.f + expf(-s));
  }
}

// ---------------------------------------------------------------------------
extern "C" void kernel_launch(void* const* d_in, const int* in_sizes, int n_in,
                              void* d_out, int out_size, void* d_ws, size_t ws_size,
                              hipStream_t stream) {
  const float* x       = (const float*)d_in[0];
  const float* w_embed = (const float*)d_in[1];
  const float* b_embed = (const float*)d_in[2];
  const float* w_cls   = (const float*)d_in[3];
  const float* tf1_w   = (const float*)d_in[4];
  const float* tf1_b   = (const float*)d_in[5];
  const float* tf2_w   = (const float*)d_in[6];
  const float* tf2_b   = (const float*)d_in[7];
  const float* in_w    = (const float*)d_in[8];
  const float* in_b    = (const float*)d_in[9];
  const float* out_w   = (const float*)d_in[10];
  const float* out_b   = (const float*)d_in[11];
  const float* c1_w    = (const float*)d_in[12];
  const float* c1_b    = (const float*)d_in[13];
  const float* c2_w    = (const float*)d_in[14];
  const float* c2_b    = (const float*)d_in[15];
  const float* l1_w    = (const float*)d_in[16];
  const float* l1_b    = (const float*)d_in[17];
  const float* l2_w    = (const float*)d_in[18];
  const float* l2_b    = (const float*)d_in[19];
  float* out = (float*)d_out;
  float* ws  = (float*)d_ws;

  // output offsets (floats)
  const long O_VS = 0, O_ACT = 320, O_A2 = 12320, O_CAS = 24320, O_RH = 264320;
  const long O_EA = 264512;
  const long O_EB = O_EA + 16L * 150 * 2048;
  const long O_HA = O_EB + 16L * 150 * 2048;
  const long O_HB = O_HA + 16L * 37 * 2048;

  // workspace layout (floats) — same total footprint as previous round:
  // whE+wlE (f16 hi/lo) exactly replace the old fp32 wpkE bytes.
  long o = 0;
  float* emb   = ws + o; o += 12000L * 2048;        // 24,576,000
  f16*   whE   = (f16*)(ws + o); o += 3L * 1024 * 2048;  // 12.58M halves
  f16*   wlE   = (f16*)(ws + o); o += 3L * 1024 * 2048;  // 12.58M halves
  // q10 (10 x 592 x 6144 = 36,372,480 floats) aliases emb+whE+wlE
  // (37,158,912 floats): all three are dead by the time proj10 runs.
  float* q10   = ws;
  float* wpk1  = ws + o; o += 3L * 128 * 2048;
  float* wpk2  = ws + o; o += 3L * 32 * 128;
  float* attnb = ws + o; o += 2L * 16 * 4 * 37 * 37;
  float* obuf  = ws + o; o += 16L * 74 * 2048;
  float* ybuf  = ws + o; o += 16L * 74 * 2048;
  float* c1o   = ws + o; o += 1184L * 128;
  float* c2o   = ws + o; o += 1184L * 32;
  float* arev  = ws + o; o += 12000;
  float* hsa   = ws + o; o += 12000;
  float* hsb   = ws + o; o += 12000;
  float* med   = ws + o; o += 16;
  float* mxv   = ws + o; o += 16;
  float* vsbuf = ws + o; o += 320;
  int* idxEA = (int*)(ws + o); o += 2400;
  int* idxEB = (int*)(ws + o); o += 2400;
  int* idxHA = (int*)(ws + o); o += 592;
  int* idxHB = (int*)(ws + o); o += 592;
  (void)ws_size; (void)in_sizes; (void)n_in; (void)out_size;

  // 1. pack conv weights
  pack_split_w_k<<<(12582912 + 255) / 256, 256, 0, stream>>>(w_embed, whE, wlE, 2048, 2048, 3);
  pack_w_k<<<(786432 + 255) / 256, 256, 0, stream>>>(c1_w, wpk1, 128, 2048, 3);
  pack_w_k<<<(12288 + 255) / 256, 256, 0, stream>>>(c2_w, wpk2, 32, 128, 3);

  // 2. embed conv (k3, 2048->2048) + relu — MFMA f16x3, windowed fp32 accum
  emb_mfma_k<<<dim3(16, 94), 256, 0, stream>>>(x, whE, wlE, b_embed, emb);

  // 3. cas (1x1, 2048->20) + relu — exact fp64-accum path (selection-critical)
  gemm32_k<1><<<dim3(1, 375), 256, 0, stream>>>(emb, w_cls, nullptr, out + O_CAS,
      12000, 20, 2048, 1, 0, 750, 1536000L, 750, 15000L, 1);

  // 4. actionness, a2
  actionness_k<<<47, 256, 0, stream>>>(out + O_CAS, out + O_ACT);
  a2_k<<<16, 256, 0, stream>>>(out + O_ACT, tf1_w, tf1_b, tf2_w, tf2_b, out + O_A2);

  // 5. video scores
  vtop_k<<<320, 256, 0, stream>>>(out + O_CAS, vsbuf);
  softmax20_k<<<16, 64, 0, stream>>>(vsbuf, out + O_VS);

  // 6. selections
  sort_topk_k<<<16, 256, 0, stream>>>(out + O_ACT, idxEA, 150, med, mxv);
  morph_k<<<16, 256, 0, stream>>>(out + O_ACT, med, mxv, arev, hsa, hsb);
  sort_topk_k<<<16, 256, 0, stream>>>(arev, idxEB, 150, nullptr, nullptr);
  sort_topk_k<<<16, 256, 0, stream>>>(hsa, idxHA, 37, nullptr, nullptr);
  sort_topk_k<<<16, 256, 0, stream>>>(hsb, idxHB, 37, nullptr, nullptr);

  gather_k<<<2400, 256, 0, stream>>>(emb, idxEA, out + O_EA, 150);
  gather_k<<<2400, 256, 0, stream>>>(emb, idxEB, out + O_EB, 150);
  gather_k<<<592, 256, 0, stream>>>(emb, idxHA, out + O_HA, 37);
  gather_k<<<592, 256, 0, stream>>>(emb, idxHB, out + O_HB, 37);

  // 7. qkv projection for ALL 10 distinct head inputs in one MFMA GEMM:
  //    M = 10*592 = 5920, N = 6144, K = 2048  (emb/whE/wlE are dead now)
  gemmx3_k<1><<<dim3(48, 47), 256, 0, stream>>>(out, in_w, in_b, q10,
      5920, 6144, 2048, O_EA, O_EB, O_HA, O_HB);

  // 8. relational heads: input indices into q10
  const int pidx[12][2] = {
    {1, 8},  // re_a_0h
    {3, 2},  // re_a_02
    {0, 3},  // re_a_03
    {5, 9},  // re_b_0h
    {7, 6},  // re_b_02
    {4, 7},  // re_b_03
    {9, 8},  // re_ab_hh
    {3, 9},  // re_ab_3h
    {8, 7},  // re_ab_h3
    {3, 7},  // re_ab_33
    {6, 3},  // re_ab_32
    {2, 7},  // re_ab_23
  };

  for (int i = 0; i < 12; ++i) {
    int iA = pidx[i][0], iB = pidx[i][1];
    attn_scores_k<<<dim3(2368, 2), 64, 0, stream>>>(q10, iA, iB, attnb);
    attn_v_k<<<dim3(592, 2), 256, 0, stream>>>(q10, iA, iB, attnb, obuf);
    gemmx3_k<0><<<dim3(16, 10), 256, 0, stream>>>(obuf, out_w, out_b, ybuf,
        1184, 2048, 2048, 0, 0, 0, 0);
    gemm32_k<0><<<dim3(4, 37), 256, 0, stream>>>(ybuf, wpk1, c1_b, c1o,
        1184, 128, 2048, 3, -1, 74, 74L * 2048, 74, 74L * 128, 2);
    gemm32_k<0><<<dim3(1, 37), 256, 0, stream>>>(c1o, wpk2, c2_b, c2o,
        1184, 32, 128, 3, -1, 74, 74L * 128, 74, 74L * 32, 2);
    head_tail_k<<<16, 320, 0, stream>>>(c2o, l1_w, l1_b, l2_w, l2_b, out + O_RH + 16L * i);
  }
}

// Round 3
// 3997.602 us; speedup vs baseline: 4.3934x; 2.0551x over previous
//
#include <hip/hip_runtime.h>

// ---------------------------------------------------------------------------
// CoLA forward on MI355X — round 5:
//  (a) emb_mfma: drop the windowed master accumulator (128 AGPRs -> 64) to go
//      from 1 wave/SIMD to 2 (straight fp32 MFMA accumulation: err ~1.2e-6,
//      still < the fp32 reference's own ~5e-6 noise), + bijective XCD-chunked
//      block swizzle (1504 = 8*188) for L2 weight-slice locality.
//  (b) batch the 12 relational heads: one dispatch per stage (attn_scores,
//      attn_v, out-proj M=14208, c1, c2, head_tail) instead of 72 small
//      serialized launches. Runtime ws_size guard falls back to the per-head
//      loop if the workspace can't hold the batched buffers.
// ---------------------------------------------------------------------------

static __device__ __forceinline__ float leaky_f(float x) { return x >= 0.f ? x : 0.2f * x; }

typedef _Float16 f16;
typedef f16 f16x4 __attribute__((ext_vector_type(4)));
typedef f16 f16x8 __attribute__((ext_vector_type(8)));
typedef float f32x4 __attribute__((ext_vector_type(4)));

// head input-pair table (indices into q10: 0..3=ea0..3, 4..7=eb0..3, 8=hA, 9=hB)
__device__ __constant__ int PIDX[12][2] = {
  {1, 8}, {3, 2}, {0, 3}, {5, 9}, {7, 6}, {4, 7},
  {9, 8}, {3, 9}, {8, 7}, {3, 7}, {6, 3}, {2, 7}};

// ---------- pack (N,KC,taps) -> (taps,N,KC) ----------
__global__ __launch_bounds__(256) void pack_w_k(const float* __restrict__ src,
                                                float* __restrict__ dst,
                                                int N, int KC, int taps) {
  long total = (long)N * KC * taps;
  long i = (long)blockIdx.x * 256 + threadIdx.x;
  if (i >= total) return;
  long nk = (long)N * KC;
  int tap = (int)(i / nk);
  long rem = i - (long)tap * nk;
  int n = (int)(rem / KC);
  int k = (int)(rem - (long)n * KC);
  dst[i] = src[((long)n * KC + k) * taps + tap];
}

// ---------- pack + f16 hi/lo split: (N,KC,taps) f32 -> (taps,N,KC) f16 x2 ----------
__global__ __launch_bounds__(256) void pack_split_w_k(const float* __restrict__ src,
                                                      f16* __restrict__ dh,
                                                      f16* __restrict__ dl,
                                                      int N, int KC, int taps) {
  long total = (long)N * KC * taps;
  long i = (long)blockIdx.x * 256 + threadIdx.x;
  if (i >= total) return;
  long nk = (long)N * KC;
  int tap = (int)(i / nk);
  long rem = i - (long)tap * nk;
  int n = (int)(rem / KC);
  int k = (int)(rem - (long)n * KC);
  float v = src[((long)n * KC + k) * taps + tap];
  f16 h = (f16)v;
  dh[i] = h;
  dl[i] = (f16)(v - (float)h);
}

// ---------------------------------------------------------------------------
// embed conv on MFMA: emb[m][n] = relu(sum_{tap,c} x[m+tap-1][c]*w[tap][n][c] + b[n])
// Straight fp32 MFMA accumulation (no window master: 64 AGPR not 128 ->
// 2 waves/SIMD). XCD-chunked swizzle: 1504 blocks = 8 XCDs x 188.
// ---------------------------------------------------------------------------
__global__ __launch_bounds__(256) void emb_mfma_k(
    const float* __restrict__ x, const f16* __restrict__ wh,
    const f16* __restrict__ wl, const float* __restrict__ bias,
    float* __restrict__ emb) {
  __shared__ f16 Ah[128][40];
  __shared__ f16 Al[128][40];
  __shared__ f16 Bh[128][40];
  __shared__ f16 Bl[128][40];
  int t = threadIdx.x;
  // bijective XCD swizzle: linear 0..1503, xcd = linear%8 gets 188 consecutive
  // work items = 2 n-columns x 94 m-rows -> 2x3.1MB weight slice stays L2-hot.
  int linear = blockIdx.y * 16 + blockIdx.x;
  int wg = (linear & 7) * 188 + (linear >> 3);
  int n0 = (wg / 94) * 128, m0 = (wg % 94) * 128;

  int sr = t >> 1;
  int sc = (t & 1) << 4;
  int am = m0 + sr;
  int at = am % 750;

  int lane = t & 63, wv = t >> 6;
  int wm = (wv >> 1) * 64, wn = (wv & 1) * 64;
  int fr = lane & 15, fg = lane >> 4;

  f32x4 acc[4][4];
#pragma unroll
  for (int i = 0; i < 4; ++i)
#pragma unroll
    for (int j = 0; j < 4; ++j) acc[i][j] = (f32x4)(0.f);

  // 192 K-chunks of 32 (3 taps x 64 chunks)
#pragma unroll 1
  for (int kt = 0; kt < 192; ++kt) {
    int tap = kt >> 6;
    int k0 = (kt & 63) << 5;

    // ---- A global load (fp32, conv shift + batch-edge zeroing) ----
    int rr = at + tap - 1;
    bool av = (am < 12000) && (rr >= 0) && (rr < 750);
    const float* ap = x + (long)(am + tap - 1) * 2048 + k0 + sc;
    float4 a4[4];
#pragma unroll
    for (int q = 0; q < 4; ++q)
      a4[q] = av ? *(const float4*)(ap + q * 4) : make_float4(0.f, 0.f, 0.f, 0.f);

    // ---- B global load (pre-split f16 hi/lo) ----
    const f16* bph = wh + ((long)tap * 2048 + (n0 + sr)) * 2048 + k0 + sc;
    const f16* bpl = wl + ((long)tap * 2048 + (n0 + sr)) * 2048 + k0 + sc;
    f16x8 bh0 = *(const f16x8*)bph;
    f16x8 bh1 = *(const f16x8*)(bph + 8);
    f16x8 bl0 = *(const f16x8*)bpl;
    f16x8 bl1 = *(const f16x8*)(bpl + 8);

    __syncthreads();   // previous chunk's frag reads done

#pragma unroll
    for (int q = 0; q < 4; ++q) {
      float xs[4] = {a4[q].x, a4[q].y, a4[q].z, a4[q].w};
      f16x4 h4, l4;
#pragma unroll
      for (int e = 0; e < 4; ++e) {
        f16 hh = (f16)xs[e];
        h4[e] = hh;
        l4[e] = (f16)(xs[e] - (float)hh);
      }
      *(f16x4*)&Ah[sr][sc + q * 4] = h4;
      *(f16x4*)&Al[sr][sc + q * 4] = l4;
    }
    *(f16x8*)&Bh[sr][sc] = bh0;
    *(f16x8*)&Bh[sr][sc + 8] = bh1;
    *(f16x8*)&Bl[sr][sc] = bl0;
    *(f16x8*)&Bl[sr][sc + 8] = bl1;
    __syncthreads();

    f16x8 fah[4], fal[4], fbh[4], fbl[4];
#pragma unroll
    for (int i = 0; i < 4; ++i) {
      fah[i] = *(const f16x8*)&Ah[wm + i * 16 + fr][fg * 8];
      fal[i] = *(const f16x8*)&Al[wm + i * 16 + fr][fg * 8];
      fbh[i] = *(const f16x8*)&Bh[wn + i * 16 + fr][fg * 8];
      fbl[i] = *(const f16x8*)&Bl[wn + i * 16 + fr][fg * 8];
    }
#pragma unroll
    for (int i = 0; i < 4; ++i)
#pragma unroll
      for (int j = 0; j < 4; ++j) {
        acc[i][j] = __builtin_amdgcn_mfma_f32_16x16x32_f16(fal[i], fbh[j], acc[i][j], 0, 0, 0);
        acc[i][j] = __builtin_amdgcn_mfma_f32_16x16x32_f16(fah[i], fbl[j], acc[i][j], 0, 0, 0);
        acc[i][j] = __builtin_amdgcn_mfma_f32_16x16x32_f16(fah[i], fbh[j], acc[i][j], 0, 0, 0);
      }
  }

#pragma unroll
  for (int i = 0; i < 4; ++i) {
#pragma unroll
    for (int j = 0; j < 4; ++j) {
      int col = n0 + wn + j * 16 + fr;
      float bb = bias[col];
#pragma unroll
      for (int r = 0; r < 4; ++r) {
        int m = m0 + wm + i * 16 + fg * 4 + r;
        if (m < 12000)
          emb[(long)m * 2048 + col] = fmaxf(acc[i][j][r] + bb, 0.f);
      }
    }
  }
}

// ---------- 32x32 fp32 GEMM variant (small N), K-tile 32 ----------
template <int DACC>
__global__ __launch_bounds__(256) void gemm32_k(
    const float* __restrict__ A, const float* __restrict__ Bw,
    const float* __restrict__ bias, float* __restrict__ C,
    int M, int N, int KC, int taps, int shift_base,
    int a_grp, long a_bstride, int c_grp, long c_bstride, int act) {
  __shared__ __align__(16) float As[32][36];
  __shared__ __align__(16) float Bs[32][36];
  int tid = threadIdx.x;
  int n0 = blockIdx.x * 32, m0 = blockIdx.y * 32;
  int tx = tid & 15, ty = tid >> 4;
  int row_l = tid >> 3;
  int kq = (tid & 7) << 2;
  float accf[2][2] = {{0.f}};
  double accd[2][2];
  if (DACC) { accd[0][0] = accd[0][1] = accd[1][0] = accd[1][1] = 0.0; }
  int tpt = KC >> 5;
  int nkt = tpt * taps;
  int am = m0 + row_l;
  int agrp = 0, ar = 0;
  if (am < M) { agrp = am / a_grp; ar = am - agrp * a_grp; }
  int bn = n0 + row_l;
  for (int kt = 0; kt < nkt; ++kt) {
    int tap = kt / tpt;
    int k0 = (kt - tap * tpt) << 5;
    float4 av = make_float4(0.f, 0.f, 0.f, 0.f);
    float4 bv = make_float4(0.f, 0.f, 0.f, 0.f);
    if (am < M) {
      int rr = ar + tap + shift_base;
      if (rr >= 0 && rr < a_grp)
        av = *(const float4*)(A + (long)agrp * a_bstride + (long)rr * KC + (k0 + kq));
    }
    if (bn < N)
      bv = *(const float4*)(Bw + ((long)tap * N + bn) * KC + (k0 + kq));
    __syncthreads();
    As[kq + 0][row_l] = av.x; As[kq + 1][row_l] = av.y;
    As[kq + 2][row_l] = av.z; As[kq + 3][row_l] = av.w;
    Bs[kq + 0][row_l] = bv.x; Bs[kq + 1][row_l] = bv.y;
    Bs[kq + 2][row_l] = bv.z; Bs[kq + 3][row_l] = bv.w;
    __syncthreads();
    float tile[2][2] = {{0.f, 0.f}, {0.f, 0.f}};
#pragma unroll
    for (int k = 0; k < 32; ++k) {
      float2 a2 = *(const float2*)&As[k][ty << 1];
      float2 b2 = *(const float2*)&Bs[k][tx << 1];
      if (DACC) {
        tile[0][0] = fmaf(a2.x, b2.x, tile[0][0]);
        tile[0][1] = fmaf(a2.x, b2.y, tile[0][1]);
        tile[1][0] = fmaf(a2.y, b2.x, tile[1][0]);
        tile[1][1] = fmaf(a2.y, b2.y, tile[1][1]);
      } else {
        accf[0][0] = fmaf(a2.x, b2.x, accf[0][0]);
        accf[0][1] = fmaf(a2.x, b2.y, accf[0][1]);
        accf[1][0] = fmaf(a2.y, b2.x, accf[1][0]);
        accf[1][1] = fmaf(a2.y, b2.y, accf[1][1]);
      }
    }
    if (DACC) {
      accd[0][0] += (double)tile[0][0]; accd[0][1] += (double)tile[0][1];
      accd[1][0] += (double)tile[1][0]; accd[1][1] += (double)tile[1][1];
    }
  }
#pragma unroll
  for (int i = 0; i < 2; ++i) {
    int m = m0 + (ty << 1) + i;
    if (m >= M) continue;
    int grp = m / c_grp, r = m - grp * c_grp;
    float* crow = C + (long)grp * c_bstride + (long)r * N;
#pragma unroll
    for (int j = 0; j < 2; ++j) {
      int n = n0 + (tx << 1) + j;
      if (n >= N) continue;
      float v = DACC ? (float)accd[i][j] : accf[i][j];
      if (bias) v += bias[n];
      if (act == 1) v = fmaxf(v, 0.f);
      else if (act == 2) v = leaky_f(v);
      crow[n] = v;
    }
  }
}

// ---------------------------------------------------------------------------
// MFMA f16x3 GEMM: C[M][N] = A[M][K] * Bw[N][K]^T + bias.
// AMODE 0: A rows contiguous. AMODE 1: A rows are the 10 head inputs in `out`.
// ---------------------------------------------------------------------------
template <int AMODE>
__global__ __launch_bounds__(256) void gemmx3_k(
    const float* __restrict__ Abase, const float* __restrict__ Bw,
    const float* __restrict__ bias, float* __restrict__ C,
    int M, int N, int K,
    long oEA, long oEB, long oHA, long oHB) {
  __shared__ _Float16 Ah[128][40];
  __shared__ _Float16 Al[128][40];
  __shared__ _Float16 Bh[128][40];
  __shared__ _Float16 Bl[128][40];
  int t = threadIdx.x;
  int m0 = blockIdx.y * 128, n0 = blockIdx.x * 128;

  int lr = t >> 3;
  int lq = t & 7;
  const float* arow[4];
  const float* brow[4];
#pragma unroll
  for (int p = 0; p < 4; ++p) {
    int m = m0 + p * 32 + lr;
    if (m < M) {
      if (AMODE == 0) {
        arow[p] = Abase + (long)m * K;
      } else {
        int inp = m / 592;
        int rem = m - inp * 592;
        int b = rem / 37;
        int r = rem - b * 37;
        long base, bstr;
        if (inp < 8) { base = (inp < 4 ? oEA : oEB) + (long)(inp & 3) * (37L * 2048); bstr = 150L * 2048; }
        else         { base = (inp == 8) ? oHA : oHB; bstr = 37L * 2048; }
        arow[p] = Abase + base + (long)b * bstr + (long)r * 2048;
      }
    } else arow[p] = nullptr;
    int n = n0 + p * 32 + lr;
    brow[p] = (n < N) ? (Bw + (long)n * K) : nullptr;
  }

  int lane = t & 63;
  int wv = t >> 6;
  int wm = (wv >> 1) * 64, wn = (wv & 1) * 64;
  int fr = lane & 15, fg = lane >> 4;

  f32x4 acc[4][4];
#pragma unroll
  for (int i = 0; i < 4; ++i)
#pragma unroll
    for (int j = 0; j < 4; ++j) acc[i][j] = (f32x4)(0.f);

  int nkt = K >> 5;
  for (int kt = 0; kt < nkt; ++kt) {
    int k0 = kt << 5;
    float4 av[4], bv[4];
#pragma unroll
    for (int p = 0; p < 4; ++p) {
      av[p] = arow[p] ? *(const float4*)(arow[p] + k0 + lq * 4) : make_float4(0.f, 0.f, 0.f, 0.f);
      bv[p] = brow[p] ? *(const float4*)(brow[p] + k0 + lq * 4) : make_float4(0.f, 0.f, 0.f, 0.f);
    }
    __syncthreads();
#pragma unroll
    for (int p = 0; p < 4; ++p) {
      int row = p * 32 + lr;
      float xs[4] = {av[p].x, av[p].y, av[p].z, av[p].w};
      f16x4 h, l;
#pragma unroll
      for (int e = 0; e < 4; ++e) {
        f16 hh = (f16)xs[e];
        h[e] = hh;
        l[e] = (f16)(xs[e] - (float)hh);
      }
      *(f16x4*)&Ah[row][lq * 4] = h;
      *(f16x4*)&Al[row][lq * 4] = l;
      float ys[4] = {bv[p].x, bv[p].y, bv[p].z, bv[p].w};
#pragma unroll
      for (int e = 0; e < 4; ++e) {
        f16 hh = (f16)ys[e];
        h[e] = hh;
        l[e] = (f16)(ys[e] - (float)hh);
      }
      *(f16x4*)&Bh[row][lq * 4] = h;
      *(f16x4*)&Bl[row][lq * 4] = l;
    }
    __syncthreads();
    f16x8 ah[4], alo[4], bh[4], blo[4];
#pragma unroll
    for (int i = 0; i < 4; ++i) {
      ah[i]  = *(const f16x8*)&Ah[wm + i * 16 + fr][fg * 8];
      alo[i] = *(const f16x8*)&Al[wm + i * 16 + fr][fg * 8];
      bh[i]  = *(const f16x8*)&Bh[wn + i * 16 + fr][fg * 8];
      blo[i] = *(const f16x8*)&Bl[wn + i * 16 + fr][fg * 8];
    }
#pragma unroll
    for (int i = 0; i < 4; ++i)
#pragma unroll
      for (int j = 0; j < 4; ++j) {
        acc[i][j] = __builtin_amdgcn_mfma_f32_16x16x32_f16(alo[i], bh[j], acc[i][j], 0, 0, 0);
        acc[i][j] = __builtin_amdgcn_mfma_f32_16x16x32_f16(ah[i], blo[j], acc[i][j], 0, 0, 0);
        acc[i][j] = __builtin_amdgcn_mfma_f32_16x16x32_f16(ah[i], bh[j], acc[i][j], 0, 0, 0);
      }
  }

#pragma unroll
  for (int i = 0; i < 4; ++i) {
#pragma unroll
    for (int j = 0; j < 4; ++j) {
      int col = n0 + wn + j * 16 + fr;
      if (col >= N) continue;
      float bb = bias ? bias[col] : 0.f;
#pragma unroll
      for (int r = 0; r < 4; ++r) {
        int m = m0 + wm + i * 16 + fg * 4 + r;
        if (m >= M) continue;
        C[(long)m * N + col] = acc[i][j][r] + bb;
      }
    }
  }
}

// ---------- actionness = sum over 20 classes (fp64 accumulate) ----------
__global__ __launch_bounds__(256) void actionness_k(const float* __restrict__ cas,
                                                    float* __restrict__ act) {
  int p = blockIdx.x * 256 + threadIdx.x;
  if (p >= 16 * 750) return;
  double s = 0.0;
#pragma unroll
  for (int c = 0; c < 20; ++c) s += (double)cas[(long)p * 20 + c];
  act[p] = (float)s;
}

// ---------- a2: two 1-channel k3 convs + relu ----------
__global__ __launch_bounds__(256) void a2_k(const float* __restrict__ act,
                                            const float* __restrict__ tf1w, const float* __restrict__ tf1b,
                                            const float* __restrict__ tf2w, const float* __restrict__ tf2b,
                                            float* __restrict__ a2out) {
  __shared__ float s0[752];
  __shared__ float s1[752];
  int b = blockIdx.x, tid = threadIdx.x;
  for (int i = tid; i < 752; i += 256) { s0[i] = 0.f; s1[i] = 0.f; }
  __syncthreads();
  for (int t = tid; t < 750; t += 256) s0[t + 1] = act[b * 750 + t];
  __syncthreads();
  float w0 = tf1w[0], w1 = tf1w[1], w2 = tf1w[2], bb1 = tf1b[0];
  for (int t = tid; t < 750; t += 256)
    s1[t + 1] = fmaxf(w0 * s0[t] + w1 * s0[t + 1] + w2 * s0[t + 2] + bb1, 0.f);
  __syncthreads();
  float u0 = tf2w[0], u1 = tf2w[1], u2 = tf2w[2], bb2 = tf2b[0];
  for (int t = tid; t < 750; t += 256)
    a2out[b * 750 + t] = fmaxf(u0 * s1[t] + u1 * s1[t + 1] + u2 * s1[t + 2] + bb2, 0.f);
}

// ---------- bitonic top-k (stable: key = score_bits<<32 | ~idx, descending) ----------
__global__ __launch_bounds__(256) void sort_topk_k(const float* __restrict__ scores,
                                                   int* __restrict__ out_idx, int K,
                                                   float* __restrict__ out_med,
                                                   float* __restrict__ out_mx) {
  __shared__ unsigned long long keys[1024];
  int b = blockIdx.x, tid = threadIdx.x;
  for (int i = tid; i < 1024; i += 256) {
    unsigned long long kv = 0ull;
    if (i < 750) {
      unsigned int bits = __float_as_uint(scores[b * 750 + i]);
      kv = ((unsigned long long)bits << 32) | (unsigned long long)(0xFFFFFFFFu - (unsigned)i);
    }
    keys[i] = kv;
  }
  __syncthreads();
  for (int k = 2; k <= 1024; k <<= 1) {
    for (int j = k >> 1; j > 0; j >>= 1) {
      for (int i = tid; i < 1024; i += 256) {
        int ixj = i ^ j;
        if (ixj > i) {
          unsigned long long a = keys[i], c = keys[ixj];
          bool sw = ((i & k) == 0) ? (a < c) : (a > c);
          if (sw) { keys[i] = c; keys[ixj] = a; }
        }
      }
      __syncthreads();
    }
  }
  for (int i = tid; i < K; i += 256)
    out_idx[b * K + i] = (int)(0xFFFFFFFFu - (unsigned int)(keys[i] & 0xFFFFFFFFull));
  if (tid == 0) {
    if (out_mx) out_mx[b] = __uint_as_float((unsigned int)(keys[0] >> 32));
    if (out_med) {
      float v1 = __uint_as_float((unsigned int)(keys[374] >> 32));
      float v2 = __uint_as_float((unsigned int)(keys[375] >> 32));
      out_med[b] = 0.5f * (v1 + v2);
    }
  }
}

// ---------- act_rev + binary morphology scores ----------
__global__ __launch_bounds__(256) void morph_k(const float* __restrict__ act,
                                               const float* __restrict__ med,
                                               const float* __restrict__ mxv,
                                               float* __restrict__ arev,
                                               float* __restrict__ hsa,
                                               float* __restrict__ hsb) {
  __shared__ float ab[756];
  int b = blockIdx.x, tid = threadIdx.x;
  float m = med[b], M = mxv[b];
  for (int i = tid; i < 756; i += 256) ab[i] = 0.f;
  __syncthreads();
  for (int t = tid; t < 750; t += 256) {
    float a = act[b * 750 + t];
    ab[t + 3] = (a > m) ? 1.f : 0.f;
    arev[b * 750 + t] = M - a;
  }
  __syncthreads();
  for (int t = tid; t < 750; t += 256) {
    float e3 = fminf(ab[t + 2], fminf(ab[t + 3], ab[t + 4]));
    float e6 = fminf(fminf(ab[t], ab[t + 1]),
                     fminf(fminf(ab[t + 2], ab[t + 3]), fminf(ab[t + 4], ab[t + 5])));
    float d3 = fmaxf(ab[t + 2], fmaxf(ab[t + 3], ab[t + 4]));
    float d6 = fmaxf(fmaxf(ab[t + 1], ab[t + 2]),
                     fmaxf(fmaxf(ab[t + 3], ab[t + 4]), fmaxf(ab[t + 5], ab[t + 6])));
    float a = act[b * 750 + t];
    hsa[b * 750 + t] = a * (e3 - e6);
    hsb[b * 750 + t] = a * (d6 - d3);
  }
}

// ---------- gather embedding rows by index ----------
__global__ __launch_bounds__(256) void gather_k(const float* __restrict__ emb,
                                                const int* __restrict__ idx,
                                                float* __restrict__ dst, int K) {
  int blk = blockIdx.x;
  int b = blk / K, i = blk - b * K;
  int t = idx[b * K + i];
  const float4* src = (const float4*)(emb + ((long)(b * 750 + t)) * 2048);
  float4* d = (float4*)(dst + (long)blk * 2048);
  for (int u = threadIdx.x; u < 512; u += 256) d[u] = src[u];
}

// ---------- video scores: per (b,c) mean of top-150 of cas[b,:,c] ----------
__global__ __launch_bounds__(256) void vtop_k(const float* __restrict__ cas,
                                              float* __restrict__ s) {
  __shared__ float v[1024];
  int b = blockIdx.x / 20, c = blockIdx.x - b * 20;
  int tid = threadIdx.x;
  for (int i = tid; i < 1024; i += 256)
    v[i] = (i < 750) ? cas[((long)(b * 750 + i)) * 20 + c] : -1.f;
  __syncthreads();
  for (int k = 2; k <= 1024; k <<= 1) {
    for (int j = k >> 1; j > 0; j >>= 1) {
      for (int i = tid; i < 1024; i += 256) {
        int ixj = i ^ j;
        if (ixj > i) {
          float a = v[i], cc = v[ixj];
          bool sw = ((i & k) == 0) ? (a < cc) : (a > cc);
          if (sw) { v[i] = cc; v[ixj] = a; }
        }
      }
      __syncthreads();
    }
  }
  if (tid == 0) {
    float sum = 0.f;
    for (int i = 0; i < 150; ++i) sum += v[i];
    s[b * 20 + c] = sum / 150.f;
  }
}

__global__ __launch_bounds__(64) void softmax20_k(const float* __restrict__ s,
                                                  float* __restrict__ out) {
  int b = blockIdx.x;
  if (threadIdx.x != 0) return;
  float mx = -3.4e38f;
  for (int c = 0; c < 20; ++c) mx = fmaxf(mx, s[b * 20 + c]);
  float e[20]; float sum = 0.f;
  for (int c = 0; c < 20; ++c) { e[c] = expf(s[b * 20 + c] - mx); sum += e[c]; }
  for (int c = 0; c < 20; ++c) out[b * 20 + c] = e[c] / sum;
}

// ---------- attention scores + softmax ----------
// blockIdx.y = local_head*2 + call; real head = head0 + local_head.
// attnb indexed by local head (so legacy per-head loop uses local 0).
__global__ __launch_bounds__(64) void attn_scores_k(const float* __restrict__ q10,
                                                    int head0,
                                                    float* __restrict__ attnb) {
  int hl = blockIdx.y >> 1, call = blockIdx.y & 1;
  int head = head0 + hl;
  int iA = PIDX[head][0], iB = PIDX[head][1];
  const float* q  = q10 + (long)(call ? iA : iB) * 592 * 6144;
  const float* kv = q10 + (long)(call ? iB : iA) * 592 * 6144;
  int x = blockIdx.x;
  int b = x / 148; int rem = x - b * 148; int h = rem / 37; int qi = rem - h * 37;
  int lane = threadIdx.x;
  const float scale = 0.04419417382415922f;   // 1/sqrt(512)
  const float* qp = q + ((long)(b * 37 + qi)) * 6144 + h * 512;
  float qr[8];
#pragma unroll
  for (int j = 0; j < 8; ++j) qr[j] = qp[lane + 64 * j] * scale;
  __shared__ float sc[37];
  for (int ki = 0; ki < 37; ++ki) {
    const float* kp = kv + ((long)(b * 37 + ki)) * 6144 + 2048 + h * 512;
    float d = 0.f;
#pragma unroll
    for (int j = 0; j < 8; ++j) d = fmaf(qr[j], kp[lane + 64 * j], d);
    for (int off = 32; off > 0; off >>= 1) d += __shfl_down(d, off, 64);
    if (lane == 0) sc[ki] = d;
  }
  __syncthreads();
  float v = (lane < 37) ? sc[lane] : -3.4e38f;
  float mx = v;
  for (int off = 32; off > 0; off >>= 1) mx = fmaxf(mx, __shfl_xor(mx, off, 64));
  float e = (lane < 37) ? expf(v - mx) : 0.f;
  float sum = e;
  for (int off = 32; off > 0; off >>= 1) sum += __shfl_xor(sum, off, 64);
  if (lane < 37)
    attnb[(((long)(((hl * 2 + call) * 16 + b) * 4 + h)) * 37 + qi) * 37 + lane] = e / sum;
}

// ---------- attn @ V ----------
__global__ __launch_bounds__(256) void attn_v_k(const float* __restrict__ q10,
                                                int head0,
                                                const float* __restrict__ attnb,
                                                float* __restrict__ obuf) {
  int hl = blockIdx.y >> 1, call = blockIdx.y & 1;
  int head = head0 + hl;
  int iA = PIDX[head][0], iB = PIDX[head][1];
  const float* kv = q10 + (long)(call ? iB : iA) * 592 * 6144;
  int x = blockIdx.x;
  int b = x / 37, qi = x - b * 37;
  int tid = threadIdx.x;
  __shared__ float at[4][37];
  if (tid < 148) {
    int h = tid / 37, ki = tid - h * 37;
    at[h][ki] = attnb[(((long)(((hl * 2 + call) * 16 + b) * 4 + h)) * 37 + qi) * 37 + ki];
  }
  __syncthreads();
  int yoff = call ? 37 : 0;
  float* op = obuf + (long)hl * (16L * 74 * 2048) + ((long)(b * 74 + yoff + qi)) * 2048;
#pragma unroll
  for (int i = 0; i < 8; ++i) {
    int c = tid + 256 * i;
    int h = c >> 9;
    float acc = 0.f;
#pragma unroll 1
    for (int ki = 0; ki < 37; ++ki)
      acc = fmaf(at[h][ki], kv[((long)(b * 37 + ki)) * 6144 + 4096 + c], acc);
    op[c] = acc;
  }
}

// ---------- l1 (74->10) + leaky + l2 (320->1) + sigmoid ----------
// blockIdx.x spans 16*nheads groups; out[blockIdx.x], c2o rows blockIdx.x*74.
__global__ __launch_bounds__(320) void head_tail_k(const float* __restrict__ c2o,
                                                   const float* __restrict__ l1w,
                                                   const float* __restrict__ l1b,
                                                   const float* __restrict__ l2w,
                                                   const float* __restrict__ l2b,
                                                   float* __restrict__ out) {
  __shared__ float h[320];
  int blk = blockIdx.x, tid = threadIdx.x;
  int c = tid / 10, j = tid - c * 10;
  float acc = l1b[j];
  for (int l = 0; l < 74; ++l)
    acc = fmaf(c2o[((long)(blk * 74 + l)) * 32 + c], l1w[j * 74 + l], acc);
  acc = leaky_f(acc);
  h[c * 10 + j] = acc * l2w[c * 10 + j];
  __syncthreads();
  if (tid == 0) {
    float s = l2b[0];
    for (int i = 0; i < 320; ++i) s += h[i];
    out[blk] = 1.f / (1.f + expf(-s));
  }
}

// ---------------------------------------------------------------------------
extern "C" void kernel_launch(void* const* d_in, const int* in_sizes, int n_in,
                              void* d_out, int out_size, void* d_ws, size_t ws_size,
                              hipStream_t stream) {
  const float* x       = (const float*)d_in[0];
  const float* w_embed = (const float*)d_in[1];
  const float* b_embed = (const float*)d_in[2];
  const float* w_cls   = (const float*)d_in[3];
  const float* tf1_w   = (const float*)d_in[4];
  const float* tf1_b   = (const float*)d_in[5];
  const float* tf2_w   = (const float*)d_in[6];
  const float* tf2_b   = (const float*)d_in[7];
  const float* in_w    = (const float*)d_in[8];
  const float* in_b    = (const float*)d_in[9];
  const float* out_w   = (const float*)d_in[10];
  const float* out_b   = (const float*)d_in[11];
  const float* c1_w    = (const float*)d_in[12];
  const float* c1_b    = (const float*)d_in[13];
  const float* c2_w    = (const float*)d_in[14];
  const float* c2_b    = (const float*)d_in[15];
  const float* l1_w    = (const float*)d_in[16];
  const float* l1_b    = (const float*)d_in[17];
  const float* l2_w    = (const float*)d_in[18];
  const float* l2_b    = (const float*)d_in[19];
  float* out = (float*)d_out;
  float* ws  = (float*)d_ws;

  // output offsets (floats)
  const long O_VS = 0, O_ACT = 320, O_A2 = 12320, O_CAS = 24320, O_RH = 264320;
  const long O_EA = 264512;
  const long O_EB = O_EA + 16L * 150 * 2048;
  const long O_HA = O_EB + 16L * 150 * 2048;
  const long O_HB = O_HA + 16L * 37 * 2048;

  // ---- workspace layout (floats) ----
  // R0: emb + whE + wlE (37,158,912) — later reused by q10 (36,372,480) and,
  // in batched mode, by ybuf12 (29,097,984). All prior occupants dead by then.
  long o = 0;
  float* emb   = ws + o; o += 12000L * 2048;
  f16*   whE   = (f16*)(ws + o); o += 3L * 1024 * 2048;
  f16*   wlE   = (f16*)(ws + o); o += 3L * 1024 * 2048;
  float* q10   = ws;
  float* wpk1  = ws + o; o += 3L * 128 * 2048;
  float* wpk2  = ws + o; o += 3L * 32 * 128;
  float* arev  = ws + o; o += 12000;
  float* hsa   = ws + o; o += 12000;
  float* hsb   = ws + o; o += 12000;
  float* med   = ws + o; o += 16;
  float* mxv   = ws + o; o += 16;
  float* vsbuf = ws + o; o += 320;
  int* idxEA = (int*)(ws + o); o += 2400;
  int* idxEB = (int*)(ws + o); o += 2400;
  int* idxHA = (int*)(ws + o); o += 592;
  int* idxHB = (int*)(ws + o); o += 592;
  long oTail = o;
  (void)in_sizes; (void)n_in; (void)out_size;

  // batched head buffers
  const long SZ_ATTNB12 = 12L * 2 * 16 * 4 * 37 * 37;   //  2,102,784
  const long SZ_OBUF12  = 12L * 16 * 74 * 2048;         // 29,097,984
  const long SZ_C1O12   = 14208L * 128;                 //  1,818,624
  const long SZ_C2O12   = 14208L * 32;                  //    454,656
  long needB = oTail + SZ_ATTNB12 + SZ_OBUF12 + SZ_C1O12 + SZ_C2O12;
  bool batched = (ws_size >= (size_t)needB * 4);

  // 1. pack conv weights
  pack_split_w_k<<<(12582912 + 255) / 256, 256, 0, stream>>>(w_embed, whE, wlE, 2048, 2048, 3);
  pack_w_k<<<(786432 + 255) / 256, 256, 0, stream>>>(c1_w, wpk1, 128, 2048, 3);
  pack_w_k<<<(12288 + 255) / 256, 256, 0, stream>>>(c2_w, wpk2, 32, 128, 3);

  // 2. embed conv (k3, 2048->2048) + relu — MFMA f16x3, straight fp32 accum
  emb_mfma_k<<<dim3(16, 94), 256, 0, stream>>>(x, whE, wlE, b_embed, emb);

  // 3. cas (1x1, 2048->20) + relu — exact fp64-accum path (selection-critical)
  gemm32_k<1><<<dim3(1, 375), 256, 0, stream>>>(emb, w_cls, nullptr, out + O_CAS,
      12000, 20, 2048, 1, 0, 750, 1536000L, 750, 15000L, 1);

  // 4. actionness, a2
  actionness_k<<<47, 256, 0, stream>>>(out + O_CAS, out + O_ACT);
  a2_k<<<16, 256, 0, stream>>>(out + O_ACT, tf1_w, tf1_b, tf2_w, tf2_b, out + O_A2);

  // 5. video scores
  vtop_k<<<320, 256, 0, stream>>>(out + O_CAS, vsbuf);
  softmax20_k<<<16, 64, 0, stream>>>(vsbuf, out + O_VS);

  // 6. selections
  sort_topk_k<<<16, 256, 0, stream>>>(out + O_ACT, idxEA, 150, med, mxv);
  morph_k<<<16, 256, 0, stream>>>(out + O_ACT, med, mxv, arev, hsa, hsb);
  sort_topk_k<<<16, 256, 0, stream>>>(arev, idxEB, 150, nullptr, nullptr);
  sort_topk_k<<<16, 256, 0, stream>>>(hsa, idxHA, 37, nullptr, nullptr);
  sort_topk_k<<<16, 256, 0, stream>>>(hsb, idxHB, 37, nullptr, nullptr);

  gather_k<<<2400, 256, 0, stream>>>(emb, idxEA, out + O_EA, 150);
  gather_k<<<2400, 256, 0, stream>>>(emb, idxEB, out + O_EB, 150);
  gather_k<<<592, 256, 0, stream>>>(emb, idxHA, out + O_HA, 37);
  gather_k<<<592, 256, 0, stream>>>(emb, idxHB, out + O_HB, 37);

  // 7. qkv projection for ALL 10 distinct head inputs (emb/whE/wlE dead now)
  gemmx3_k<1><<<dim3(48, 47), 256, 0, stream>>>(out, in_w, in_b, q10,
      5920, 6144, 2048, O_EA, O_EB, O_HA, O_HB);

  // 8. relational heads
  if (batched) {
    float* attnbB = ws + oTail;
    float* obufB  = attnbB + SZ_ATTNB12;
    float* c1oB   = obufB + SZ_OBUF12;
    float* c2oB   = c1oB + SZ_C1O12;
    float* ybufB  = ws;               // aliases R0 (q10 dead after attn_v)

    attn_scores_k<<<dim3(2368, 24), 64, 0, stream>>>(q10, 0, attnbB);
    attn_v_k<<<dim3(592, 24), 256, 0, stream>>>(q10, 0, attnbB, obufB);
    gemmx3_k<0><<<dim3(16, 111), 256, 0, stream>>>(obufB, out_w, out_b, ybufB,
        14208, 2048, 2048, 0, 0, 0, 0);
    gemm32_k<0><<<dim3(4, 444), 256, 0, stream>>>(ybufB, wpk1, c1_b, c1oB,
        14208, 128, 2048, 3, -1, 74, 74L * 2048, 74, 74L * 128, 2);
    gemm32_k<0><<<dim3(1, 444), 256, 0, stream>>>(c1oB, wpk2, c2_b, c2oB,
        14208, 32, 128, 3, -1, 74, 74L * 128, 74, 74L * 32, 2);
    head_tail_k<<<192, 320, 0, stream>>>(c2oB, l1_w, l1_b, l2_w, l2_b, out + O_RH);
  } else {
    // legacy per-head loop (known-good 173MB footprint)
    float* attnbL = ws + oTail;
    float* obufL  = attnbL + 2L * 16 * 4 * 37 * 37;
    float* ybufL  = obufL + 16L * 74 * 2048;
    float* c1oL   = ybufL + 16L * 74 * 2048;
    float* c2oL   = c1oL + 1184L * 128;
    for (int i = 0; i < 12; ++i) {
      attn_scores_k<<<dim3(2368, 2), 64, 0, stream>>>(q10, i, attnbL);
      attn_v_k<<<dim3(592, 2), 256, 0, stream>>>(q10, i, attnbL, obufL);
      gemmx3_k<0><<<dim3(16, 10), 256, 0, stream>>>(obufL, out_w, out_b, ybufL,
          1184, 2048, 2048, 0, 0, 0, 0);
      gemm32_k<0><<<dim3(4, 37), 256, 0, stream>>>(ybufL, wpk1, c1_b, c1oL,
          1184, 128, 2048, 3, -1, 74, 74L * 2048, 74, 74L * 128, 2);
      gemm32_k<0><<<dim3(1, 37), 256, 0, stream>>>(c1oL, wpk2, c2_b, c2oL,
          1184, 32, 128, 3, -1, 74, 74L * 128, 74, 74L * 32, 2);
      head_tail_k<<<16, 320, 0, stream>>>(c2oL, l1_w, l1_b, l2_w, l2_b, out + O_RH + 16L * i);
    }
  }
}

// Round 4
// 3446.493 us; speedup vs baseline: 5.0960x; 1.1599x over previous
//
#include <hip/hip_runtime.h>

// ---------------------------------------------------------------------------
// CoLA forward on MI355X — round 6:
//  (a) unified MFMA f16x3 conv/GEMM kernel (gemmf3_k) with B pre-packed in
//      fragment-linear layout read DIRECTLY from global (no B LDS round-trip):
//      LDS traffic/chunk 96KB -> 48KB, LDS/block 40KB -> 20KB. Used for the
//      embed conv (bit-identical MFMA sequence to round 5 -> selection-safe)
//      and for the c1 conv (previously fp32 gemm32, ~44GB LDS traffic).
//  (b) everything else unchanged from round 5.
// ---------------------------------------------------------------------------

static __device__ __forceinline__ float leaky_f(float x) { return x >= 0.f ? x : 0.2f * x; }

typedef _Float16 f16;
typedef f16 f16x4 __attribute__((ext_vector_type(4)));
typedef f16 f16x8 __attribute__((ext_vector_type(8)));
typedef float f32x4 __attribute__((ext_vector_type(4)));

// head input-pair table (indices into q10: 0..3=ea0..3, 4..7=eb0..3, 8=hA, 9=hB)
__device__ __constant__ int PIDX[12][2] = {
  {1, 8}, {3, 2}, {0, 3}, {5, 9}, {7, 6}, {4, 7},
  {9, 8}, {3, 9}, {8, 7}, {3, 7}, {6, 3}, {2, 7}};

// ---------- pack (N,KC,taps) -> (taps,N,KC) ----------
__global__ __launch_bounds__(256) void pack_w_k(const float* __restrict__ src,
                                                float* __restrict__ dst,
                                                int N, int KC, int taps) {
  long total = (long)N * KC * taps;
  long i = (long)blockIdx.x * 256 + threadIdx.x;
  if (i >= total) return;
  long nk = (long)N * KC;
  int tap = (int)(i / nk);
  long rem = i - (long)tap * nk;
  int n = (int)(rem / KC);
  int k = (int)(rem - (long)n * KC);
  dst[i] = src[((long)n * KC + k) * taps + tap];
}

// ---------- pack conv weights (N,KC,taps) f32 -> MFMA fragment-linear f16 hi/lo ----------
// Output: frag index f = (tap*(KC/32) + kc)*(N/16) + g; each frag-pair is
// 1024 halves: [hi: lane*8+e | lo: 512 + lane*8+e], where
// n = g*16 + (lane&15), k = kc*32 + (lane>>4)*8 + e.
__global__ __launch_bounds__(256) void pack_frag_w_k(const float* __restrict__ src,
                                                     f16* __restrict__ dst,
                                                     int N, int KC, int taps) {
  int KCd32 = KC >> 5, gN = N >> 4;
  long total = (long)taps * KCd32 * gN * 512;
  long i = (long)blockIdx.x * 256 + threadIdx.x;
  if (i >= total) return;
  int e = (int)(i & 7);
  int lane = (int)((i >> 3) & 63);
  long rem = i >> 9;
  int g = (int)(rem % gN); rem /= gN;
  int kc = (int)(rem % KCd32);
  int tap = (int)(rem / KCd32);
  int n = g * 16 + (lane & 15);
  int k = kc * 32 + (lane >> 4) * 8 + e;
  float v = src[((long)n * KC + k) * taps + tap];
  f16 h = (f16)v;
  long f = ((long)tap * KCd32 + kc) * gN + g;
  dst[f * 1024 + lane * 8 + e] = h;
  dst[f * 1024 + 512 + lane * 8 + e] = (f16)(v - (float)h);
}

// ---------------------------------------------------------------------------
// Unified MFMA f16x3 grouped-conv GEMM:
//   C[m][n] = act( sum_{tap,k} A[m + tap + shift][k] * W[tap][n][k] + bias[n] )
// A fp32 (rows linear, groups of a_grp rows; tap shift zero-padded at group
// edges), split to f16 hi/lo in LDS. B pre-packed fragment-linear (see
// pack_frag_w_k), loaded directly global->reg (coalesced 1KB per fragment).
// 128x128 tile, 4 waves of 64x64. 1D grid; optional 8-XCD chunk swizzle.
// ---------------------------------------------------------------------------
__global__ __launch_bounds__(256) void gemmf3_k(
    const float* __restrict__ A, const f16* __restrict__ Bf,
    const float* __restrict__ bias, float* __restrict__ C,
    int M, int N, int KC, int taps, int shift_base, int a_grp,
    int mblocks, int swz, int act) {
  __shared__ f16 Ah[128][40];
  __shared__ f16 Al[128][40];
  int t = threadIdx.x;
  int NB = gridDim.x;
  int linear = blockIdx.x;
  int wg = swz ? ((linear & 7) * (NB >> 3) + (linear >> 3)) : linear;
  int n0 = (wg / mblocks) * 128, m0 = (wg % mblocks) * 128;

  int sr = t >> 1;              // staged row 0..127
  int sc = (t & 1) << 4;        // 16-float half of the 32-float chunk
  int am = m0 + sr;
  int ar = am % a_grp;

  int lane = t & 63, wv = t >> 6;
  int wm = (wv >> 1) * 64, wn = (wv & 1) * 64;
  int fr = lane & 15, fg = lane >> 4;

  int KCd32 = KC >> 5, gN = N >> 4;
  int g0 = ((n0 + wn) >> 4);

  f32x4 acc[4][4];
#pragma unroll
  for (int i = 0; i < 4; ++i)
#pragma unroll
    for (int j = 0; j < 4; ++j) acc[i][j] = (f32x4)(0.f);

  for (int tap = 0; tap < taps; ++tap) {
    int rr = ar + tap + shift_base;
    bool av = (am < M) && (rr >= 0) && (rr < a_grp);
    const float* ap = A + (long)(am + tap + shift_base) * KC + sc;
    long fb = ((long)tap * KCd32) * gN;
#pragma unroll 1
    for (int kc = 0; kc < KCd32; ++kc) {
      // ---- B fragments direct from global (coalesced 1KB per frag) ----
      const f16* fp = Bf + (fb + (long)kc * gN + g0) * 1024 + lane * 8;
      f16x8 fbh[4], fbl[4];
#pragma unroll
      for (int j = 0; j < 4; ++j) {
        fbh[j] = *(const f16x8*)(fp + (long)j * 1024);
        fbl[j] = *(const f16x8*)(fp + (long)j * 1024 + 512);
      }
      // ---- A global load (fp32, conv shift + group-edge zeroing) ----
      float4 a4[4];
#pragma unroll
      for (int q = 0; q < 4; ++q)
        a4[q] = av ? *(const float4*)(ap + kc * 32 + q * 4)
                   : make_float4(0.f, 0.f, 0.f, 0.f);

      __syncthreads();   // previous chunk's A-frag reads done
#pragma unroll
      for (int q = 0; q < 4; ++q) {
        float xs[4] = {a4[q].x, a4[q].y, a4[q].z, a4[q].w};
        f16x4 h4, l4;
#pragma unroll
        for (int e = 0; e < 4; ++e) {
          f16 hh = (f16)xs[e];
          h4[e] = hh;
          l4[e] = (f16)(xs[e] - (float)hh);
        }
        *(f16x4*)&Ah[sr][sc + q * 4] = h4;
        *(f16x4*)&Al[sr][sc + q * 4] = l4;
      }
      __syncthreads();

      f16x8 fah[4], fal[4];
#pragma unroll
      for (int i = 0; i < 4; ++i) {
        fah[i] = *(const f16x8*)&Ah[wm + i * 16 + fr][fg * 8];
        fal[i] = *(const f16x8*)&Al[wm + i * 16 + fr][fg * 8];
      }
#pragma unroll
      for (int i = 0; i < 4; ++i)
#pragma unroll
        for (int j = 0; j < 4; ++j) {
          acc[i][j] = __builtin_amdgcn_mfma_f32_16x16x32_f16(fal[i], fbh[j], acc[i][j], 0, 0, 0);
          acc[i][j] = __builtin_amdgcn_mfma_f32_16x16x32_f16(fah[i], fbl[j], acc[i][j], 0, 0, 0);
          acc[i][j] = __builtin_amdgcn_mfma_f32_16x16x32_f16(fah[i], fbh[j], acc[i][j], 0, 0, 0);
        }
    }
  }

  // epilogue: C/D layout col=lane&15, row=(lane>>4)*4+reg
#pragma unroll
  for (int i = 0; i < 4; ++i) {
#pragma unroll
    for (int j = 0; j < 4; ++j) {
      int col = n0 + wn + j * 16 + fr;
      if (col >= N) continue;
      float bb = bias ? bias[col] : 0.f;
#pragma unroll
      for (int r = 0; r < 4; ++r) {
        int m = m0 + wm + i * 16 + fg * 4 + r;
        if (m >= M) continue;
        float v = acc[i][j][r] + bb;
        if (act == 1) v = fmaxf(v, 0.f);
        else if (act == 2) v = leaky_f(v);
        C[(long)m * N + col] = v;
      }
    }
  }
}

// ---------- 32x32 fp32 GEMM variant (small N), K-tile 32 ----------
template <int DACC>
__global__ __launch_bounds__(256) void gemm32_k(
    const float* __restrict__ A, const float* __restrict__ Bw,
    const float* __restrict__ bias, float* __restrict__ C,
    int M, int N, int KC, int taps, int shift_base,
    int a_grp, long a_bstride, int c_grp, long c_bstride, int act) {
  __shared__ __align__(16) float As[32][36];
  __shared__ __align__(16) float Bs[32][36];
  int tid = threadIdx.x;
  int n0 = blockIdx.x * 32, m0 = blockIdx.y * 32;
  int tx = tid & 15, ty = tid >> 4;
  int row_l = tid >> 3;
  int kq = (tid & 7) << 2;
  float accf[2][2] = {{0.f}};
  double accd[2][2];
  if (DACC) { accd[0][0] = accd[0][1] = accd[1][0] = accd[1][1] = 0.0; }
  int tpt = KC >> 5;
  int nkt = tpt * taps;
  int am = m0 + row_l;
  int agrp = 0, ar = 0;
  if (am < M) { agrp = am / a_grp; ar = am - agrp * a_grp; }
  int bn = n0 + row_l;
  for (int kt = 0; kt < nkt; ++kt) {
    int tap = kt / tpt;
    int k0 = (kt - tap * tpt) << 5;
    float4 av = make_float4(0.f, 0.f, 0.f, 0.f);
    float4 bv = make_float4(0.f, 0.f, 0.f, 0.f);
    if (am < M) {
      int rr = ar + tap + shift_base;
      if (rr >= 0 && rr < a_grp)
        av = *(const float4*)(A + (long)agrp * a_bstride + (long)rr * KC + (k0 + kq));
    }
    if (bn < N)
      bv = *(const float4*)(Bw + ((long)tap * N + bn) * KC + (k0 + kq));
    __syncthreads();
    As[kq + 0][row_l] = av.x; As[kq + 1][row_l] = av.y;
    As[kq + 2][row_l] = av.z; As[kq + 3][row_l] = av.w;
    Bs[kq + 0][row_l] = bv.x; Bs[kq + 1][row_l] = bv.y;
    Bs[kq + 2][row_l] = bv.z; Bs[kq + 3][row_l] = bv.w;
    __syncthreads();
    float tile[2][2] = {{0.f, 0.f}, {0.f, 0.f}};
#pragma unroll
    for (int k = 0; k < 32; ++k) {
      float2 a2 = *(const float2*)&As[k][ty << 1];
      float2 b2 = *(const float2*)&Bs[k][tx << 1];
      if (DACC) {
        tile[0][0] = fmaf(a2.x, b2.x, tile[0][0]);
        tile[0][1] = fmaf(a2.x, b2.y, tile[0][1]);
        tile[1][0] = fmaf(a2.y, b2.x, tile[1][0]);
        tile[1][1] = fmaf(a2.y, b2.y, tile[1][1]);
      } else {
        accf[0][0] = fmaf(a2.x, b2.x, accf[0][0]);
        accf[0][1] = fmaf(a2.x, b2.y, accf[0][1]);
        accf[1][0] = fmaf(a2.y, b2.x, accf[1][0]);
        accf[1][1] = fmaf(a2.y, b2.y, accf[1][1]);
      }
    }
    if (DACC) {
      accd[0][0] += (double)tile[0][0]; accd[0][1] += (double)tile[0][1];
      accd[1][0] += (double)tile[1][0]; accd[1][1] += (double)tile[1][1];
    }
  }
#pragma unroll
  for (int i = 0; i < 2; ++i) {
    int m = m0 + (ty << 1) + i;
    if (m >= M) continue;
    int grp = m / c_grp, r = m - grp * c_grp;
    float* crow = C + (long)grp * c_bstride + (long)r * N;
#pragma unroll
    for (int j = 0; j < 2; ++j) {
      int n = n0 + (tx << 1) + j;
      if (n >= N) continue;
      float v = DACC ? (float)accd[i][j] : accf[i][j];
      if (bias) v += bias[n];
      if (act == 1) v = fmaxf(v, 0.f);
      else if (act == 2) v = leaky_f(v);
      crow[n] = v;
    }
  }
}

// ---------------------------------------------------------------------------
// MFMA f16x3 GEMM (in-kernel B split): C = A*Bw^T + bias.
// AMODE 0: A rows contiguous. AMODE 1: A rows are the 10 head inputs in `out`.
// ---------------------------------------------------------------------------
template <int AMODE>
__global__ __launch_bounds__(256) void gemmx3_k(
    const float* __restrict__ Abase, const float* __restrict__ Bw,
    const float* __restrict__ bias, float* __restrict__ C,
    int M, int N, int K,
    long oEA, long oEB, long oHA, long oHB) {
  __shared__ _Float16 Ah[128][40];
  __shared__ _Float16 Al[128][40];
  __shared__ _Float16 Bh[128][40];
  __shared__ _Float16 Bl[128][40];
  int t = threadIdx.x;
  int m0 = blockIdx.y * 128, n0 = blockIdx.x * 128;

  int lr = t >> 3;
  int lq = t & 7;
  const float* arow[4];
  const float* brow[4];
#pragma unroll
  for (int p = 0; p < 4; ++p) {
    int m = m0 + p * 32 + lr;
    if (m < M) {
      if (AMODE == 0) {
        arow[p] = Abase + (long)m * K;
      } else {
        int inp = m / 592;
        int rem = m - inp * 592;
        int b = rem / 37;
        int r = rem - b * 37;
        long base, bstr;
        if (inp < 8) { base = (inp < 4 ? oEA : oEB) + (long)(inp & 3) * (37L * 2048); bstr = 150L * 2048; }
        else         { base = (inp == 8) ? oHA : oHB; bstr = 37L * 2048; }
        arow[p] = Abase + base + (long)b * bstr + (long)r * 2048;
      }
    } else arow[p] = nullptr;
    int n = n0 + p * 32 + lr;
    brow[p] = (n < N) ? (Bw + (long)n * K) : nullptr;
  }

  int lane = t & 63;
  int wv = t >> 6;
  int wm = (wv >> 1) * 64, wn = (wv & 1) * 64;
  int fr = lane & 15, fg = lane >> 4;

  f32x4 acc[4][4];
#pragma unroll
  for (int i = 0; i < 4; ++i)
#pragma unroll
    for (int j = 0; j < 4; ++j) acc[i][j] = (f32x4)(0.f);

  int nkt = K >> 5;
  for (int kt = 0; kt < nkt; ++kt) {
    int k0 = kt << 5;
    float4 av[4], bv[4];
#pragma unroll
    for (int p = 0; p < 4; ++p) {
      av[p] = arow[p] ? *(const float4*)(arow[p] + k0 + lq * 4) : make_float4(0.f, 0.f, 0.f, 0.f);
      bv[p] = brow[p] ? *(const float4*)(brow[p] + k0 + lq * 4) : make_float4(0.f, 0.f, 0.f, 0.f);
    }
    __syncthreads();
#pragma unroll
    for (int p = 0; p < 4; ++p) {
      int row = p * 32 + lr;
      float xs[4] = {av[p].x, av[p].y, av[p].z, av[p].w};
      f16x4 h, l;
#pragma unroll
      for (int e = 0; e < 4; ++e) {
        f16 hh = (f16)xs[e];
        h[e] = hh;
        l[e] = (f16)(xs[e] - (float)hh);
      }
      *(f16x4*)&Ah[row][lq * 4] = h;
      *(f16x4*)&Al[row][lq * 4] = l;
      float ys[4] = {bv[p].x, bv[p].y, bv[p].z, bv[p].w};
#pragma unroll
      for (int e = 0; e < 4; ++e) {
        f16 hh = (f16)ys[e];
        h[e] = hh;
        l[e] = (f16)(ys[e] - (float)hh);
      }
      *(f16x4*)&Bh[row][lq * 4] = h;
      *(f16x4*)&Bl[row][lq * 4] = l;
    }
    __syncthreads();
    f16x8 ah[4], alo[4], bh[4], blo[4];
#pragma unroll
    for (int i = 0; i < 4; ++i) {
      ah[i]  = *(const f16x8*)&Ah[wm + i * 16 + fr][fg * 8];
      alo[i] = *(const f16x8*)&Al[wm + i * 16 + fr][fg * 8];
      bh[i]  = *(const f16x8*)&Bh[wn + i * 16 + fr][fg * 8];
      blo[i] = *(const f16x8*)&Bl[wn + i * 16 + fr][fg * 8];
    }
#pragma unroll
    for (int i = 0; i < 4; ++i)
#pragma unroll
      for (int j = 0; j < 4; ++j) {
        acc[i][j] = __builtin_amdgcn_mfma_f32_16x16x32_f16(alo[i], bh[j], acc[i][j], 0, 0, 0);
        acc[i][j] = __builtin_amdgcn_mfma_f32_16x16x32_f16(ah[i], blo[j], acc[i][j], 0, 0, 0);
        acc[i][j] = __builtin_amdgcn_mfma_f32_16x16x32_f16(ah[i], bh[j], acc[i][j], 0, 0, 0);
      }
  }

#pragma unroll
  for (int i = 0; i < 4; ++i) {
#pragma unroll
    for (int j = 0; j < 4; ++j) {
      int col = n0 + wn + j * 16 + fr;
      if (col >= N) continue;
      float bb = bias ? bias[col] : 0.f;
#pragma unroll
      for (int r = 0; r < 4; ++r) {
        int m = m0 + wm + i * 16 + fg * 4 + r;
        if (m >= M) continue;
        C[(long)m * N + col] = acc[i][j][r] + bb;
      }
    }
  }
}

// ---------- actionness = sum over 20 classes (fp64 accumulate) ----------
__global__ __launch_bounds__(256) void actionness_k(const float* __restrict__ cas,
                                                    float* __restrict__ act) {
  int p = blockIdx.x * 256 + threadIdx.x;
  if (p >= 16 * 750) return;
  double s = 0.0;
#pragma unroll
  for (int c = 0; c < 20; ++c) s += (double)cas[(long)p * 20 + c];
  act[p] = (float)s;
}

// ---------- a2: two 1-channel k3 convs + relu ----------
__global__ __launch_bounds__(256) void a2_k(const float* __restrict__ act,
                                            const float* __restrict__ tf1w, const float* __restrict__ tf1b,
                                            const float* __restrict__ tf2w, const float* __restrict__ tf2b,
                                            float* __restrict__ a2out) {
  __shared__ float s0[752];
  __shared__ float s1[752];
  int b = blockIdx.x, tid = threadIdx.x;
  for (int i = tid; i < 752; i += 256) { s0[i] = 0.f; s1[i] = 0.f; }
  __syncthreads();
  for (int t = tid; t < 750; t += 256) s0[t + 1] = act[b * 750 + t];
  __syncthreads();
  float w0 = tf1w[0], w1 = tf1w[1], w2 = tf1w[2], bb1 = tf1b[0];
  for (int t = tid; t < 750; t += 256)
    s1[t + 1] = fmaxf(w0 * s0[t] + w1 * s0[t + 1] + w2 * s0[t + 2] + bb1, 0.f);
  __syncthreads();
  float u0 = tf2w[0], u1 = tf2w[1], u2 = tf2w[2], bb2 = tf2b[0];
  for (int t = tid; t < 750; t += 256)
    a2out[b * 750 + t] = fmaxf(u0 * s1[t] + u1 * s1[t + 1] + u2 * s1[t + 2] + bb2, 0.f);
}

// ---------- bitonic top-k (stable: key = score_bits<<32 | ~idx, descending) ----------
__global__ __launch_bounds__(256) void sort_topk_k(const float* __restrict__ scores,
                                                   int* __restrict__ out_idx, int K,
                                                   float* __restrict__ out_med,
                                                   float* __restrict__ out_mx) {
  __shared__ unsigned long long keys[1024];
  int b = blockIdx.x, tid = threadIdx.x;
  for (int i = tid; i < 1024; i += 256) {
    unsigned long long kv = 0ull;
    if (i < 750) {
      unsigned int bits = __float_as_uint(scores[b * 750 + i]);
      kv = ((unsigned long long)bits << 32) | (unsigned long long)(0xFFFFFFFFu - (unsigned)i);
    }
    keys[i] = kv;
  }
  __syncthreads();
  for (int k = 2; k <= 1024; k <<= 1) {
    for (int j = k >> 1; j > 0; j >>= 1) {
      for (int i = tid; i < 1024; i += 256) {
        int ixj = i ^ j;
        if (ixj > i) {
          unsigned long long a = keys[i], c = keys[ixj];
          bool sw = ((i & k) == 0) ? (a < c) : (a > c);
          if (sw) { keys[i] = c; keys[ixj] = a; }
        }
      }
      __syncthreads();
    }
  }
  for (int i = tid; i < K; i += 256)
    out_idx[b * K + i] = (int)(0xFFFFFFFFu - (unsigned int)(keys[i] & 0xFFFFFFFFull));
  if (tid == 0) {
    if (out_mx) out_mx[b] = __uint_as_float((unsigned int)(keys[0] >> 32));
    if (out_med) {
      float v1 = __uint_as_float((unsigned int)(keys[374] >> 32));
      float v2 = __uint_as_float((unsigned int)(keys[375] >> 32));
      out_med[b] = 0.5f * (v1 + v2);
    }
  }
}

// ---------- act_rev + binary morphology scores ----------
__global__ __launch_bounds__(256) void morph_k(const float* __restrict__ act,
                                               const float* __restrict__ med,
                                               const float* __restrict__ mxv,
                                               float* __restrict__ arev,
                                               float* __restrict__ hsa,
                                               float* __restrict__ hsb) {
  __shared__ float ab[756];
  int b = blockIdx.x, tid = threadIdx.x;
  float m = med[b], M = mxv[b];
  for (int i = tid; i < 756; i += 256) ab[i] = 0.f;
  __syncthreads();
  for (int t = tid; t < 750; t += 256) {
    float a = act[b * 750 + t];
    ab[t + 3] = (a > m) ? 1.f : 0.f;
    arev[b * 750 + t] = M - a;
  }
  __syncthreads();
  for (int t = tid; t < 750; t += 256) {
    float e3 = fminf(ab[t + 2], fminf(ab[t + 3], ab[t + 4]));
    float e6 = fminf(fminf(ab[t], ab[t + 1]),
                     fminf(fminf(ab[t + 2], ab[t + 3]), fminf(ab[t + 4], ab[t + 5])));
    float d3 = fmaxf(ab[t + 2], fmaxf(ab[t + 3], ab[t + 4]));
    float d6 = fmaxf(fmaxf(ab[t + 1], ab[t + 2]),
                     fmaxf(fmaxf(ab[t + 3], ab[t + 4]), fmaxf(ab[t + 5], ab[t + 6])));
    float a = act[b * 750 + t];
    hsa[b * 750 + t] = a * (e3 - e6);
    hsb[b * 750 + t] = a * (d6 - d3);
  }
}

// ---------- gather embedding rows by index ----------
__global__ __launch_bounds__(256) void gather_k(const float* __restrict__ emb,
                                                const int* __restrict__ idx,
                                                float* __restrict__ dst, int K) {
  int blk = blockIdx.x;
  int b = blk / K, i = blk - b * K;
  int t = idx[b * K + i];
  const float4* src = (const float4*)(emb + ((long)(b * 750 + t)) * 2048);
  float4* d = (float4*)(dst + (long)blk * 2048);
  for (int u = threadIdx.x; u < 512; u += 256) d[u] = src[u];
}

// ---------- video scores: per (b,c) mean of top-150 of cas[b,:,c] ----------
__global__ __launch_bounds__(256) void vtop_k(const float* __restrict__ cas,
                                              float* __restrict__ s) {
  __shared__ float v[1024];
  int b = blockIdx.x / 20, c = blockIdx.x - b * 20;
  int tid = threadIdx.x;
  for (int i = tid; i < 1024; i += 256)
    v[i] = (i < 750) ? cas[((long)(b * 750 + i)) * 20 + c] : -1.f;
  __syncthreads();
  for (int k = 2; k <= 1024; k <<= 1) {
    for (int j = k >> 1; j > 0; j >>= 1) {
      for (int i = tid; i < 1024; i += 256) {
        int ixj = i ^ j;
        if (ixj > i) {
          float a = v[i], cc = v[ixj];
          bool sw = ((i & k) == 0) ? (a < cc) : (a > cc);
          if (sw) { v[i] = cc; v[ixj] = a; }
        }
      }
      __syncthreads();
    }
  }
  if (tid == 0) {
    float sum = 0.f;
    for (int i = 0; i < 150; ++i) sum += v[i];
    s[b * 20 + c] = sum / 150.f;
  }
}

__global__ __launch_bounds__(64) void softmax20_k(const float* __restrict__ s,
                                                  float* __restrict__ out) {
  int b = blockIdx.x;
  if (threadIdx.x != 0) return;
  float mx = -3.4e38f;
  for (int c = 0; c < 20; ++c) mx = fmaxf(mx, s[b * 20 + c]);
  float e[20]; float sum = 0.f;
  for (int c = 0; c < 20; ++c) { e[c] = expf(s[b * 20 + c] - mx); sum += e[c]; }
  for (int c = 0; c < 20; ++c) out[b * 20 + c] = e[c] / sum;
}

// ---------- attention scores + softmax ----------
__global__ __launch_bounds__(64) void attn_scores_k(const float* __restrict__ q10,
                                                    int head0,
                                                    float* __restrict__ attnb) {
  int hl = blockIdx.y >> 1, call = blockIdx.y & 1;
  int head = head0 + hl;
  int iA = PIDX[head][0], iB = PIDX[head][1];
  const float* q  = q10 + (long)(call ? iA : iB) * 592 * 6144;
  const float* kv = q10 + (long)(call ? iB : iA) * 592 * 6144;
  int x = blockIdx.x;
  int b = x / 148; int rem = x - b * 148; int h = rem / 37; int qi = rem - h * 37;
  int lane = threadIdx.x;
  const float scale = 0.04419417382415922f;   // 1/sqrt(512)
  const float* qp = q + ((long)(b * 37 + qi)) * 6144 + h * 512;
  float qr[8];
#pragma unroll
  for (int j = 0; j < 8; ++j) qr[j] = qp[lane + 64 * j] * scale;
  __shared__ float sc[37];
  for (int ki = 0; ki < 37; ++ki) {
    const float* kp = kv + ((long)(b * 37 + ki)) * 6144 + 2048 + h * 512;
    float d = 0.f;
#pragma unroll
    for (int j = 0; j < 8; ++j) d = fmaf(qr[j], kp[lane + 64 * j], d);
    for (int off = 32; off > 0; off >>= 1) d += __shfl_down(d, off, 64);
    if (lane == 0) sc[ki] = d;
  }
  __syncthreads();
  float v = (lane < 37) ? sc[lane] : -3.4e38f;
  float mx = v;
  for (int off = 32; off > 0; off >>= 1) mx = fmaxf(mx, __shfl_xor(mx, off, 64));
  float e = (lane < 37) ? expf(v - mx) : 0.f;
  float sum = e;
  for (int off = 32; off > 0; off >>= 1) sum += __shfl_xor(sum, off, 64);
  if (lane < 37)
    attnb[(((long)(((hl * 2 + call) * 16 + b) * 4 + h)) * 37 + qi) * 37 + lane] = e / sum;
}

// ---------- attn @ V ----------
__global__ __launch_bounds__(256) void attn_v_k(const float* __restrict__ q10,
                                                int head0,
                                                const float* __restrict__ attnb,
                                                float* __restrict__ obuf) {
  int hl = blockIdx.y >> 1, call = blockIdx.y & 1;
  int head = head0 + hl;
  int iA = PIDX[head][0], iB = PIDX[head][1];
  const float* kv = q10 + (long)(call ? iB : iA) * 592 * 6144;
  int x = blockIdx.x;
  int b = x / 37, qi = x - b * 37;
  int tid = threadIdx.x;
  __shared__ float at[4][37];
  if (tid < 148) {
    int h = tid / 37, ki = tid - h * 37;
    at[h][ki] = attnb[(((long)(((hl * 2 + call) * 16 + b) * 4 + h)) * 37 + qi) * 37 + ki];
  }
  __syncthreads();
  int yoff = call ? 37 : 0;
  float* op = obuf + (long)hl * (16L * 74 * 2048) + ((long)(b * 74 + yoff + qi)) * 2048;
#pragma unroll
  for (int i = 0; i < 8; ++i) {
    int c = tid + 256 * i;
    int h = c >> 9;
    float acc = 0.f;
#pragma unroll 1
    for (int ki = 0; ki < 37; ++ki)
      acc = fmaf(at[h][ki], kv[((long)(b * 37 + ki)) * 6144 + 4096 + c], acc);
    op[c] = acc;
  }
}

// ---------- l1 (74->10) + leaky + l2 (320->1) + sigmoid ----------
__global__ __launch_bounds__(320) void head_tail_k(const float* __restrict__ c2o,
                                                   const float* __restrict__ l1w,
                                                   const float* __restrict__ l1b,
                                                   const float* __restrict__ l2w,
                                                   const float* __restrict__ l2b,
                                                   float* __restrict__ out) {
  __shared__ float h[320];
  int blk = blockIdx.x, tid = threadIdx.x;
  int c = tid / 10, j = tid - c * 10;
  float acc = l1b[j];
  for (int l = 0; l < 74; ++l)
    acc = fmaf(c2o[((long)(blk * 74 + l)) * 32 + c], l1w[j * 74 + l], acc);
  acc = leaky_f(acc);
  h[c * 10 + j] = acc * l2w[c * 10 + j];
  __syncthreads();
  if (tid == 0) {
    float s = l2b[0];
    for (int i = 0; i < 320; ++i) s += h[i];
    out[blk] = 1.f / (1.f + expf(-s));
  }
}

// ---------------------------------------------------------------------------
extern "C" void kernel_launch(void* const* d_in, const int* in_sizes, int n_in,
                              void* d_out, int out_size, void* d_ws, size_t ws_size,
                              hipStream_t stream) {
  const float* x       = (const float*)d_in[0];
  const float* w_embed = (const float*)d_in[1];
  const float* b_embed = (const float*)d_in[2];
  const float* w_cls   = (const float*)d_in[3];
  const float* tf1_w   = (const float*)d_in[4];
  const float* tf1_b   = (const float*)d_in[5];
  const float* tf2_w   = (const float*)d_in[6];
  const float* tf2_b   = (const float*)d_in[7];
  const float* in_w    = (const float*)d_in[8];
  const float* in_b    = (const float*)d_in[9];
  const float* out_w   = (const float*)d_in[10];
  const float* out_b   = (const float*)d_in[11];
  const float* c1_w    = (const float*)d_in[12];
  const float* c1_b    = (const float*)d_in[13];
  const float* c2_w    = (const float*)d_in[14];
  const float* c2_b    = (const float*)d_in[15];
  const float* l1_w    = (const float*)d_in[16];
  const float* l1_b    = (const float*)d_in[17];
  const float* l2_w    = (const float*)d_in[18];
  const float* l2_b    = (const float*)d_in[19];
  float* out = (float*)d_out;
  float* ws  = (float*)d_ws;

  // output offsets (floats)
  const long O_VS = 0, O_ACT = 320, O_A2 = 12320, O_CAS = 24320, O_RH = 264320;
  const long O_EA = 264512;
  const long O_EB = O_EA + 16L * 150 * 2048;
  const long O_HA = O_EB + 16L * 150 * 2048;
  const long O_HB = O_HA + 16L * 37 * 2048;

  // ---- workspace layout (floats) — same footprint as round 5 ----
  long o = 0;
  float* emb   = ws + o; o += 12000L * 2048;          // 24,576,000
  f16*   embWf = (f16*)(ws + o); o += 12582912;        // frag-packed w_embed (25.17M halves)
  float* q10   = ws;                                   // aliases emb+embWf (dead by then)
  f16*   c1Wf  = (f16*)(ws + o); o += 786432;          // frag-packed c1_w (1.57M halves)
  float* wpk2  = ws + o; o += 3L * 32 * 128;
  float* arev  = ws + o; o += 12000;
  float* hsa   = ws + o; o += 12000;
  float* hsb   = ws + o; o += 12000;
  float* med   = ws + o; o += 16;
  float* mxv   = ws + o; o += 16;
  float* vsbuf = ws + o; o += 320;
  int* idxEA = (int*)(ws + o); o += 2400;
  int* idxEB = (int*)(ws + o); o += 2400;
  int* idxHA = (int*)(ws + o); o += 592;
  int* idxHB = (int*)(ws + o); o += 592;
  long oTail = o;
  (void)in_sizes; (void)n_in; (void)out_size;

  const long SZ_ATTNB12 = 12L * 2 * 16 * 4 * 37 * 37;
  const long SZ_OBUF12  = 12L * 16 * 74 * 2048;
  const long SZ_C1O12   = 14208L * 128;
  const long SZ_C2O12   = 14208L * 32;
  long needB = oTail + SZ_ATTNB12 + SZ_OBUF12 + SZ_C1O12 + SZ_C2O12;
  bool batched = (ws_size >= (size_t)needB * 4);

  // 1. pack conv weights (fragment-linear f16 hi/lo for MFMA paths)
  pack_frag_w_k<<<(12582912 + 255) / 256, 256, 0, stream>>>(w_embed, embWf, 2048, 2048, 3);
  pack_frag_w_k<<<(786432 + 255) / 256, 256, 0, stream>>>(c1_w, c1Wf, 128, 2048, 3);
  pack_w_k<<<(12288 + 255) / 256, 256, 0, stream>>>(c2_w, wpk2, 32, 128, 3);

  // 2. embed conv (k3, 2048->2048) + relu — MFMA f16x3, B direct-from-global.
  //    MFMA sequence bit-identical to round 5 (selection-safe).
  gemmf3_k<<<1504, 256, 0, stream>>>(x, embWf, b_embed, emb,
      12000, 2048, 2048, 3, -1, 750, 94, 1, 1);

  // 3. cas (1x1, 2048->20) + relu — exact fp64-accum path (selection-critical)
  gemm32_k<1><<<dim3(1, 375), 256, 0, stream>>>(emb, w_cls, nullptr, out + O_CAS,
      12000, 20, 2048, 1, 0, 750, 1536000L, 750, 15000L, 1);

  // 4. actionness, a2
  actionness_k<<<47, 256, 0, stream>>>(out + O_CAS, out + O_ACT);
  a2_k<<<16, 256, 0, stream>>>(out + O_ACT, tf1_w, tf1_b, tf2_w, tf2_b, out + O_A2);

  // 5. video scores
  vtop_k<<<320, 256, 0, stream>>>(out + O_CAS, vsbuf);
  softmax20_k<<<16, 64, 0, stream>>>(vsbuf, out + O_VS);

  // 6. selections
  sort_topk_k<<<16, 256, 0, stream>>>(out + O_ACT, idxEA, 150, med, mxv);
  morph_k<<<16, 256, 0, stream>>>(out + O_ACT, med, mxv, arev, hsa, hsb);
  sort_topk_k<<<16, 256, 0, stream>>>(arev, idxEB, 150, nullptr, nullptr);
  sort_topk_k<<<16, 256, 0, stream>>>(hsa, idxHA, 37, nullptr, nullptr);
  sort_topk_k<<<16, 256, 0, stream>>>(hsb, idxHB, 37, nullptr, nullptr);

  gather_k<<<2400, 256, 0, stream>>>(emb, idxEA, out + O_EA, 150);
  gather_k<<<2400, 256, 0, stream>>>(emb, idxEB, out + O_EB, 150);
  gather_k<<<592, 256, 0, stream>>>(emb, idxHA, out + O_HA, 37);
  gather_k<<<592, 256, 0, stream>>>(emb, idxHB, out + O_HB, 37);

  // 7. qkv projection for ALL 10 distinct head inputs (emb/embWf dead now)
  gemmx3_k<1><<<dim3(48, 47), 256, 0, stream>>>(out, in_w, in_b, q10,
      5920, 6144, 2048, O_EA, O_EB, O_HA, O_HB);

  // 8. relational heads
  if (batched) {
    float* attnbB = ws + oTail;
    float* obufB  = attnbB + SZ_ATTNB12;
    float* c1oB   = obufB + SZ_OBUF12;
    float* c2oB   = c1oB + SZ_C1O12;
    float* ybufB  = ws;               // aliases q10 region (dead after attn_v)

    attn_scores_k<<<dim3(2368, 24), 64, 0, stream>>>(q10, 0, attnbB);
    attn_v_k<<<dim3(592, 24), 256, 0, stream>>>(q10, 0, attnbB, obufB);
    gemmx3_k<0><<<dim3(16, 111), 256, 0, stream>>>(obufB, out_w, out_b, ybufB,
        14208, 2048, 2048, 0, 0, 0, 0);
    // c1 conv (k3, 2048->128) + leaky — MFMA f16x3, grouped rows of 74
    gemmf3_k<<<111, 256, 0, stream>>>(ybufB, c1Wf, c1_b, c1oB,
        14208, 128, 2048, 3, -1, 74, 111, 0, 2);
    gemm32_k<0><<<dim3(1, 444), 256, 0, stream>>>(c1oB, wpk2, c2_b, c2oB,
        14208, 32, 128, 3, -1, 74, 74L * 128, 74, 74L * 32, 2);
    head_tail_k<<<192, 320, 0, stream>>>(c2oB, l1_w, l1_b, l2_w, l2_b, out + O_RH);
  } else {
    // legacy per-head loop
    float* attnbL = ws + oTail;
    float* obufL  = attnbL + 2L * 16 * 4 * 37 * 37;
    float* ybufL  = obufL + 16L * 74 * 2048;
    float* c1oL   = ybufL + 16L * 74 * 2048;
    float* c2oL   = c1oL + 1184L * 128;
    for (int i = 0; i < 12; ++i) {
      attn_scores_k<<<dim3(2368, 2), 64, 0, stream>>>(q10, i, attnbL);
      attn_v_k<<<dim3(592, 2), 256, 0, stream>>>(q10, i, attnbL, obufL);
      gemmx3_k<0><<<dim3(16, 10), 256, 0, stream>>>(obufL, out_w, out_b, ybufL,
          1184, 2048, 2048, 0, 0, 0, 0);
      gemmf3_k<<<10, 256, 0, stream>>>(ybufL, c1Wf, c1_b, c1oL,
          1184, 128, 2048, 3, -1, 74, 10, 0, 2);
      gemm32_k<0><<<dim3(1, 37), 256, 0, stream>>>(c1oL, wpk2, c2_b, c2oL,
          1184, 32, 128, 3, -1, 74, 74L * 128, 74, 74L * 32, 2);
      head_tail_k<<<16, 320, 0, stream>>>(c2oL, l1_w, l1_b, l2_w, l2_b, out + O_RH + 16L * i);
    }
  }
}

// Round 5
// 2862.058 us; speedup vs baseline: 6.1366x; 1.2042x over previous
//
#include <hip/hip_runtime.h>

// ---------------------------------------------------------------------------
// CoLA forward on MI355X — round 7:
//  (a) gemmf3: single-barrier double-buffered A staging (prefetch next chunk
//      during MFMA). Same MFMA order -> bit-identical emb (selection-safe).
//  (b) attention restructure for data reuse: scores = 4-wave block per
//      (call,b,h) (K-panel read ~once instead of 37x); attn@V = block per
//      (call,b,8-qi) (V-panel read once per 8 qi instead of per qi).
//      Per-output accumulation order unchanged -> bit-identical.
//  (c) launch fusion: 3 sorts -> 1 dispatch, 4 gathers -> 1 dispatch.
// ---------------------------------------------------------------------------

static __device__ __forceinline__ float leaky_f(float x) { return x >= 0.f ? x : 0.2f * x; }

typedef _Float16 f16;
typedef f16 f16x4 __attribute__((ext_vector_type(4)));
typedef f16 f16x8 __attribute__((ext_vector_type(8)));
typedef float f32x4 __attribute__((ext_vector_type(4)));

// head input-pair table (indices into q10: 0..3=ea0..3, 4..7=eb0..3, 8=hA, 9=hB)
__device__ __constant__ int PIDX[12][2] = {
  {1, 8}, {3, 2}, {0, 3}, {5, 9}, {7, 6}, {4, 7},
  {9, 8}, {3, 9}, {8, 7}, {3, 7}, {6, 3}, {2, 7}};

// ---------- pack (N,KC,taps) -> (taps,N,KC) ----------
__global__ __launch_bounds__(256) void pack_w_k(const float* __restrict__ src,
                                                float* __restrict__ dst,
                                                int N, int KC, int taps) {
  long total = (long)N * KC * taps;
  long i = (long)blockIdx.x * 256 + threadIdx.x;
  if (i >= total) return;
  long nk = (long)N * KC;
  int tap = (int)(i / nk);
  long rem = i - (long)tap * nk;
  int n = (int)(rem / KC);
  int k = (int)(rem - (long)n * KC);
  dst[i] = src[((long)n * KC + k) * taps + tap];
}

// ---------- pack conv weights (N,KC,taps) f32 -> MFMA fragment-linear f16 hi/lo ----------
__global__ __launch_bounds__(256) void pack_frag_w_k(const float* __restrict__ src,
                                                     f16* __restrict__ dst,
                                                     int N, int KC, int taps) {
  int KCd32 = KC >> 5, gN = N >> 4;
  long total = (long)taps * KCd32 * gN * 512;
  long i = (long)blockIdx.x * 256 + threadIdx.x;
  if (i >= total) return;
  int e = (int)(i & 7);
  int lane = (int)((i >> 3) & 63);
  long rem = i >> 9;
  int g = (int)(rem % gN); rem /= gN;
  int kc = (int)(rem % KCd32);
  int tap = (int)(rem / KCd32);
  int n = g * 16 + (lane & 15);
  int k = kc * 32 + (lane >> 4) * 8 + e;
  float v = src[((long)n * KC + k) * taps + tap];
  f16 h = (f16)v;
  long f = ((long)tap * KCd32 + kc) * gN + g;
  dst[f * 1024 + lane * 8 + e] = h;
  dst[f * 1024 + 512 + lane * 8 + e] = (f16)(v - (float)h);
}

// ---------------------------------------------------------------------------
// Unified MFMA f16x3 grouped-conv GEMM, B fragment-linear direct from global,
// A staged through DOUBLE-BUFFERED LDS with ONE barrier per K-chunk.
// MFMA order identical to rounds 5/6 (bit-exact emb -> selection-safe).
// ---------------------------------------------------------------------------
__global__ __launch_bounds__(256) void gemmf3_k(
    const float* __restrict__ A, const f16* __restrict__ Bf,
    const float* __restrict__ bias, float* __restrict__ C,
    int M, int N, int KC, int taps, int shift_base, int a_grp,
    int mblocks, int swz, int act) {
  __shared__ f16 Ah[2][128][40];
  __shared__ f16 Al[2][128][40];
  int t = threadIdx.x;
  int NB = gridDim.x;
  int linear = blockIdx.x;
  int wg = swz ? ((linear & 7) * (NB >> 3) + (linear >> 3)) : linear;
  int n0 = (wg / mblocks) * 128, m0 = (wg % mblocks) * 128;

  int sr = t >> 1, sc = (t & 1) << 4;
  int am = m0 + sr;
  int ar = am % a_grp;
  const float* rbase = A + (long)am * KC;

  int lane = t & 63, wv = t >> 6;
  int wm = (wv >> 1) * 64, wn = (wv & 1) * 64;
  int fr = lane & 15, fg = lane >> 4;

  int KCd32 = KC >> 5, gN = N >> 4;
  int g0 = (n0 + wn) >> 4;
  int nkt = taps * KCd32;

  f32x4 acc[4][4];
#pragma unroll
  for (int i = 0; i < 4; ++i)
#pragma unroll
    for (int j = 0; j < 4; ++j) acc[i][j] = (f32x4)(0.f);

  auto loada = [&](int kt, float4* a4) {
    int tap = kt / KCd32;
    int kc = kt - tap * KCd32;
    int rr = ar + tap + shift_base;
    bool av = (am < M) && (rr >= 0) && (rr < a_grp);
    const float* ap = rbase + (long)(tap + shift_base) * KC + (kc << 5) + sc;
#pragma unroll
    for (int q = 0; q < 4; ++q)
      a4[q] = av ? *(const float4*)(ap + q * 4) : make_float4(0.f, 0.f, 0.f, 0.f);
  };
  auto storea = [&](int buf, const float4* a4) {
#pragma unroll
    for (int q = 0; q < 4; ++q) {
      float xs[4] = {a4[q].x, a4[q].y, a4[q].z, a4[q].w};
      f16x4 h4, l4;
#pragma unroll
      for (int e = 0; e < 4; ++e) {
        f16 hh = (f16)xs[e];
        h4[e] = hh;
        l4[e] = (f16)(xs[e] - (float)hh);
      }
      *(f16x4*)&Ah[buf][sr][sc + q * 4] = h4;
      *(f16x4*)&Al[buf][sr][sc + q * 4] = l4;
    }
  };

  float4 a4[4];
  loada(0, a4);
  storea(0, a4);

#pragma unroll 1
  for (int kt = 0; kt < nkt; ++kt) {
    int buf = kt & 1;
    // B fragments for the CURRENT chunk, direct from global
    const f16* fp = Bf + ((long)kt * gN + g0) * 1024 + lane * 8;
    f16x8 fbh[4], fbl[4];
#pragma unroll
    for (int j = 0; j < 4; ++j) {
      fbh[j] = *(const f16x8*)(fp + (long)j * 1024);
      fbl[j] = *(const f16x8*)(fp + (long)j * 1024 + 512);
    }
    bool havn = (kt + 1 < nkt);
    if (havn) loada(kt + 1, a4);            // prefetch next A chunk (global)
    __syncthreads();                        // buf's stores visible; prev reads of buf^1 done
    f16x8 fah[4], fal[4];
#pragma unroll
    for (int i = 0; i < 4; ++i) {
      fah[i] = *(const f16x8*)&Ah[buf][wm + i * 16 + fr][fg * 8];
      fal[i] = *(const f16x8*)&Al[buf][wm + i * 16 + fr][fg * 8];
    }
    if (havn) storea(buf ^ 1, a4);          // overlaps with MFMA below
#pragma unroll
    for (int i = 0; i < 4; ++i)
#pragma unroll
      for (int j = 0; j < 4; ++j) {
        acc[i][j] = __builtin_amdgcn_mfma_f32_16x16x32_f16(fal[i], fbh[j], acc[i][j], 0, 0, 0);
        acc[i][j] = __builtin_amdgcn_mfma_f32_16x16x32_f16(fah[i], fbl[j], acc[i][j], 0, 0, 0);
        acc[i][j] = __builtin_amdgcn_mfma_f32_16x16x32_f16(fah[i], fbh[j], acc[i][j], 0, 0, 0);
      }
  }

  // epilogue: C/D layout col=lane&15, row=(lane>>4)*4+reg
#pragma unroll
  for (int i = 0; i < 4; ++i) {
#pragma unroll
    for (int j = 0; j < 4; ++j) {
      int col = n0 + wn + j * 16 + fr;
      if (col >= N) continue;
      float bb = bias ? bias[col] : 0.f;
#pragma unroll
      for (int r = 0; r < 4; ++r) {
        int m = m0 + wm + i * 16 + fg * 4 + r;
        if (m >= M) continue;
        float v = acc[i][j][r] + bb;
        if (act == 1) v = fmaxf(v, 0.f);
        else if (act == 2) v = leaky_f(v);
        C[(long)m * N + col] = v;
      }
    }
  }
}

// ---------- 32x32 fp32 GEMM variant (small N), K-tile 32 ----------
template <int DACC>
__global__ __launch_bounds__(256) void gemm32_k(
    const float* __restrict__ A, const float* __restrict__ Bw,
    const float* __restrict__ bias, float* __restrict__ C,
    int M, int N, int KC, int taps, int shift_base,
    int a_grp, long a_bstride, int c_grp, long c_bstride, int act) {
  __shared__ __align__(16) float As[32][36];
  __shared__ __align__(16) float Bs[32][36];
  int tid = threadIdx.x;
  int n0 = blockIdx.x * 32, m0 = blockIdx.y * 32;
  int tx = tid & 15, ty = tid >> 4;
  int row_l = tid >> 3;
  int kq = (tid & 7) << 2;
  float accf[2][2] = {{0.f}};
  double accd[2][2];
  if (DACC) { accd[0][0] = accd[0][1] = accd[1][0] = accd[1][1] = 0.0; }
  int tpt = KC >> 5;
  int nkt = tpt * taps;
  int am = m0 + row_l;
  int agrp = 0, ar = 0;
  if (am < M) { agrp = am / a_grp; ar = am - agrp * a_grp; }
  int bn = n0 + row_l;
  for (int kt = 0; kt < nkt; ++kt) {
    int tap = kt / tpt;
    int k0 = (kt - tap * tpt) << 5;
    float4 av = make_float4(0.f, 0.f, 0.f, 0.f);
    float4 bv = make_float4(0.f, 0.f, 0.f, 0.f);
    if (am < M) {
      int rr = ar + tap + shift_base;
      if (rr >= 0 && rr < a_grp)
        av = *(const float4*)(A + (long)agrp * a_bstride + (long)rr * KC + (k0 + kq));
    }
    if (bn < N)
      bv = *(const float4*)(Bw + ((long)tap * N + bn) * KC + (k0 + kq));
    __syncthreads();
    As[kq + 0][row_l] = av.x; As[kq + 1][row_l] = av.y;
    As[kq + 2][row_l] = av.z; As[kq + 3][row_l] = av.w;
    Bs[kq + 0][row_l] = bv.x; Bs[kq + 1][row_l] = bv.y;
    Bs[kq + 2][row_l] = bv.z; Bs[kq + 3][row_l] = bv.w;
    __syncthreads();
    float tile[2][2] = {{0.f, 0.f}, {0.f, 0.f}};
#pragma unroll
    for (int k = 0; k < 32; ++k) {
      float2 a2 = *(const float2*)&As[k][ty << 1];
      float2 b2 = *(const float2*)&Bs[k][tx << 1];
      if (DACC) {
        tile[0][0] = fmaf(a2.x, b2.x, tile[0][0]);
        tile[0][1] = fmaf(a2.x, b2.y, tile[0][1]);
        tile[1][0] = fmaf(a2.y, b2.x, tile[1][0]);
        tile[1][1] = fmaf(a2.y, b2.y, tile[1][1]);
      } else {
        accf[0][0] = fmaf(a2.x, b2.x, accf[0][0]);
        accf[0][1] = fmaf(a2.x, b2.y, accf[0][1]);
        accf[1][0] = fmaf(a2.y, b2.x, accf[1][0]);
        accf[1][1] = fmaf(a2.y, b2.y, accf[1][1]);
      }
    }
    if (DACC) {
      accd[0][0] += (double)tile[0][0]; accd[0][1] += (double)tile[0][1];
      accd[1][0] += (double)tile[1][0]; accd[1][1] += (double)tile[1][1];
    }
  }
#pragma unroll
  for (int i = 0; i < 2; ++i) {
    int m = m0 + (ty << 1) + i;
    if (m >= M) continue;
    int grp = m / c_grp, r = m - grp * c_grp;
    float* crow = C + (long)grp * c_bstride + (long)r * N;
#pragma unroll
    for (int j = 0; j < 2; ++j) {
      int n = n0 + (tx << 1) + j;
      if (n >= N) continue;
      float v = DACC ? (float)accd[i][j] : accf[i][j];
      if (bias) v += bias[n];
      if (act == 1) v = fmaxf(v, 0.f);
      else if (act == 2) v = leaky_f(v);
      crow[n] = v;
    }
  }
}

// ---------------------------------------------------------------------------
// MFMA f16x3 GEMM (in-kernel B split): C = A*Bw^T + bias. (proj10 / out-proj)
// ---------------------------------------------------------------------------
template <int AMODE>
__global__ __launch_bounds__(256) void gemmx3_k(
    const float* __restrict__ Abase, const float* __restrict__ Bw,
    const float* __restrict__ bias, float* __restrict__ C,
    int M, int N, int K,
    long oEA, long oEB, long oHA, long oHB) {
  __shared__ _Float16 Ah[128][40];
  __shared__ _Float16 Al[128][40];
  __shared__ _Float16 Bh[128][40];
  __shared__ _Float16 Bl[128][40];
  int t = threadIdx.x;
  int m0 = blockIdx.y * 128, n0 = blockIdx.x * 128;

  int lr = t >> 3;
  int lq = t & 7;
  const float* arow[4];
  const float* brow[4];
#pragma unroll
  for (int p = 0; p < 4; ++p) {
    int m = m0 + p * 32 + lr;
    if (m < M) {
      if (AMODE == 0) {
        arow[p] = Abase + (long)m * K;
      } else {
        int inp = m / 592;
        int rem = m - inp * 592;
        int b = rem / 37;
        int r = rem - b * 37;
        long base, bstr;
        if (inp < 8) { base = (inp < 4 ? oEA : oEB) + (long)(inp & 3) * (37L * 2048); bstr = 150L * 2048; }
        else         { base = (inp == 8) ? oHA : oHB; bstr = 37L * 2048; }
        arow[p] = Abase + base + (long)b * bstr + (long)r * 2048;
      }
    } else arow[p] = nullptr;
    int n = n0 + p * 32 + lr;
    brow[p] = (n < N) ? (Bw + (long)n * K) : nullptr;
  }

  int lane = t & 63;
  int wv = t >> 6;
  int wm = (wv >> 1) * 64, wn = (wv & 1) * 64;
  int fr = lane & 15, fg = lane >> 4;

  f32x4 acc[4][4];
#pragma unroll
  for (int i = 0; i < 4; ++i)
#pragma unroll
    for (int j = 0; j < 4; ++j) acc[i][j] = (f32x4)(0.f);

  int nkt = K >> 5;
  for (int kt = 0; kt < nkt; ++kt) {
    int k0 = kt << 5;
    float4 av[4], bv[4];
#pragma unroll
    for (int p = 0; p < 4; ++p) {
      av[p] = arow[p] ? *(const float4*)(arow[p] + k0 + lq * 4) : make_float4(0.f, 0.f, 0.f, 0.f);
      bv[p] = brow[p] ? *(const float4*)(brow[p] + k0 + lq * 4) : make_float4(0.f, 0.f, 0.f, 0.f);
    }
    __syncthreads();
#pragma unroll
    for (int p = 0; p < 4; ++p) {
      int row = p * 32 + lr;
      float xs[4] = {av[p].x, av[p].y, av[p].z, av[p].w};
      f16x4 h, l;
#pragma unroll
      for (int e = 0; e < 4; ++e) {
        f16 hh = (f16)xs[e];
        h[e] = hh;
        l[e] = (f16)(xs[e] - (float)hh);
      }
      *(f16x4*)&Ah[row][lq * 4] = h;
      *(f16x4*)&Al[row][lq * 4] = l;
      float ys[4] = {bv[p].x, bv[p].y, bv[p].z, bv[p].w};
#pragma unroll
      for (int e = 0; e < 4; ++e) {
        f16 hh = (f16)ys[e];
        h[e] = hh;
        l[e] = (f16)(ys[e] - (float)hh);
      }
      *(f16x4*)&Bh[row][lq * 4] = h;
      *(f16x4*)&Bl[row][lq * 4] = l;
    }
    __syncthreads();
    f16x8 ah[4], alo[4], bh[4], blo[4];
#pragma unroll
    for (int i = 0; i < 4; ++i) {
      ah[i]  = *(const f16x8*)&Ah[wm + i * 16 + fr][fg * 8];
      alo[i] = *(const f16x8*)&Al[wm + i * 16 + fr][fg * 8];
      bh[i]  = *(const f16x8*)&Bh[wn + i * 16 + fr][fg * 8];
      blo[i] = *(const f16x8*)&Bl[wn + i * 16 + fr][fg * 8];
    }
#pragma unroll
    for (int i = 0; i < 4; ++i)
#pragma unroll
      for (int j = 0; j < 4; ++j) {
        acc[i][j] = __builtin_amdgcn_mfma_f32_16x16x32_f16(alo[i], bh[j], acc[i][j], 0, 0, 0);
        acc[i][j] = __builtin_amdgcn_mfma_f32_16x16x32_f16(ah[i], blo[j], acc[i][j], 0, 0, 0);
        acc[i][j] = __builtin_amdgcn_mfma_f32_16x16x32_f16(ah[i], bh[j], acc[i][j], 0, 0, 0);
      }
  }

#pragma unroll
  for (int i = 0; i < 4; ++i) {
#pragma unroll
    for (int j = 0; j < 4; ++j) {
      int col = n0 + wn + j * 16 + fr;
      if (col >= N) continue;
      float bb = bias ? bias[col] : 0.f;
#pragma unroll
      for (int r = 0; r < 4; ++r) {
        int m = m0 + wm + i * 16 + fg * 4 + r;
        if (m >= M) continue;
        C[(long)m * N + col] = acc[i][j][r] + bb;
      }
    }
  }
}

// ---------- actionness = sum over 20 classes (fp64 accumulate) ----------
__global__ __launch_bounds__(256) void actionness_k(const float* __restrict__ cas,
                                                    float* __restrict__ act) {
  int p = blockIdx.x * 256 + threadIdx.x;
  if (p >= 16 * 750) return;
  double s = 0.0;
#pragma unroll
  for (int c = 0; c < 20; ++c) s += (double)cas[(long)p * 20 + c];
  act[p] = (float)s;
}

// ---------- a2: two 1-channel k3 convs + relu ----------
__global__ __launch_bounds__(256) void a2_k(const float* __restrict__ act,
                                            const float* __restrict__ tf1w, const float* __restrict__ tf1b,
                                            const float* __restrict__ tf2w, const float* __restrict__ tf2b,
                                            float* __restrict__ a2out) {
  __shared__ float s0[752];
  __shared__ float s1[752];
  int b = blockIdx.x, tid = threadIdx.x;
  for (int i = tid; i < 752; i += 256) { s0[i] = 0.f; s1[i] = 0.f; }
  __syncthreads();
  for (int t = tid; t < 750; t += 256) s0[t + 1] = act[b * 750 + t];
  __syncthreads();
  float w0 = tf1w[0], w1 = tf1w[1], w2 = tf1w[2], bb1 = tf1b[0];
  for (int t = tid; t < 750; t += 256)
    s1[t + 1] = fmaxf(w0 * s0[t] + w1 * s0[t + 1] + w2 * s0[t + 2] + bb1, 0.f);
  __syncthreads();
  float u0 = tf2w[0], u1 = tf2w[1], u2 = tf2w[2], bb2 = tf2b[0];
  for (int t = tid; t < 750; t += 256)
    a2out[b * 750 + t] = fmaxf(u0 * s1[t] + u1 * s1[t + 1] + u2 * s1[t + 2] + bb2, 0.f);
}

// ---------- bitonic top-k (stable: key = score_bits<<32 | ~idx, descending) ----------
__global__ __launch_bounds__(256) void sort_topk_k(const float* __restrict__ scores,
                                                   int* __restrict__ out_idx, int K,
                                                   float* __restrict__ out_med,
                                                   float* __restrict__ out_mx) {
  __shared__ unsigned long long keys[1024];
  int b = blockIdx.x, tid = threadIdx.x;
  for (int i = tid; i < 1024; i += 256) {
    unsigned long long kv = 0ull;
    if (i < 750) {
      unsigned int bits = __float_as_uint(scores[b * 750 + i]);
      kv = ((unsigned long long)bits << 32) | (unsigned long long)(0xFFFFFFFFu - (unsigned)i);
    }
    keys[i] = kv;
  }
  __syncthreads();
  for (int k = 2; k <= 1024; k <<= 1) {
    for (int j = k >> 1; j > 0; j >>= 1) {
      for (int i = tid; i < 1024; i += 256) {
        int ixj = i ^ j;
        if (ixj > i) {
          unsigned long long a = keys[i], c = keys[ixj];
          bool sw = ((i & k) == 0) ? (a < c) : (a > c);
          if (sw) { keys[i] = c; keys[ixj] = a; }
        }
      }
      __syncthreads();
    }
  }
  for (int i = tid; i < K; i += 256)
    out_idx[b * K + i] = (int)(0xFFFFFFFFu - (unsigned int)(keys[i] & 0xFFFFFFFFull));
  if (tid == 0) {
    if (out_mx) out_mx[b] = __uint_as_float((unsigned int)(keys[0] >> 32));
    if (out_med) {
      float v1 = __uint_as_float((unsigned int)(keys[374] >> 32));
      float v2 = __uint_as_float((unsigned int)(keys[375] >> 32));
      out_med[b] = 0.5f * (v1 + v2);
    }
  }
}

// ---------- fused 3-way sort (arev/hsa/hsb) in ONE dispatch, grid 48 ----------
__global__ __launch_bounds__(256) void sort3_k(const float* __restrict__ arev,
                                               const float* __restrict__ hsa,
                                               const float* __restrict__ hsb,
                                               int* __restrict__ idxEB,
                                               int* __restrict__ idxHA,
                                               int* __restrict__ idxHB) {
  __shared__ unsigned long long keys[1024];
  int which = blockIdx.x >> 4;
  int b = blockIdx.x & 15, tid = threadIdx.x;
  const float* s = (which == 0) ? arev : (which == 1) ? hsa : hsb;
  int* oi = (which == 0) ? idxEB : (which == 1) ? idxHA : idxHB;
  int K = (which == 0) ? 150 : 37;
  for (int i = tid; i < 1024; i += 256) {
    unsigned long long kv = 0ull;
    if (i < 750) {
      unsigned int bits = __float_as_uint(s[b * 750 + i]);
      kv = ((unsigned long long)bits << 32) | (unsigned long long)(0xFFFFFFFFu - (unsigned)i);
    }
    keys[i] = kv;
  }
  __syncthreads();
  for (int k = 2; k <= 1024; k <<= 1) {
    for (int j = k >> 1; j > 0; j >>= 1) {
      for (int i = tid; i < 1024; i += 256) {
        int ixj = i ^ j;
        if (ixj > i) {
          unsigned long long a = keys[i], c = keys[ixj];
          bool sw = ((i & k) == 0) ? (a < c) : (a > c);
          if (sw) { keys[i] = c; keys[ixj] = a; }
        }
      }
      __syncthreads();
    }
  }
  for (int i = tid; i < K; i += 256)
    oi[b * K + i] = (int)(0xFFFFFFFFu - (unsigned int)(keys[i] & 0xFFFFFFFFull));
}

// ---------- act_rev + binary morphology scores ----------
__global__ __launch_bounds__(256) void morph_k(const float* __restrict__ act,
                                               const float* __restrict__ med,
                                               const float* __restrict__ mxv,
                                               float* __restrict__ arev,
                                               float* __restrict__ hsa,
                                               float* __restrict__ hsb) {
  __shared__ float ab[756];
  int b = blockIdx.x, tid = threadIdx.x;
  float m = med[b], M = mxv[b];
  for (int i = tid; i < 756; i += 256) ab[i] = 0.f;
  __syncthreads();
  for (int t = tid; t < 750; t += 256) {
    float a = act[b * 750 + t];
    ab[t + 3] = (a > m) ? 1.f : 0.f;
    arev[b * 750 + t] = M - a;
  }
  __syncthreads();
  for (int t = tid; t < 750; t += 256) {
    float e3 = fminf(ab[t + 2], fminf(ab[t + 3], ab[t + 4]));
    float e6 = fminf(fminf(ab[t], ab[t + 1]),
                     fminf(fminf(ab[t + 2], ab[t + 3]), fminf(ab[t + 4], ab[t + 5])));
    float d3 = fmaxf(ab[t + 2], fmaxf(ab[t + 3], ab[t + 4]));
    float d6 = fmaxf(fmaxf(ab[t + 1], ab[t + 2]),
                     fmaxf(fmaxf(ab[t + 3], ab[t + 4]), fmaxf(ab[t + 5], ab[t + 6])));
    float a = act[b * 750 + t];
    hsa[b * 750 + t] = a * (e3 - e6);
    hsb[b * 750 + t] = a * (d6 - d3);
  }
}

// ---------- all 4 gathers in ONE dispatch, grid 5984 ----------
__global__ __launch_bounds__(256) void gather4_k(const float* __restrict__ emb,
                                                 const int* __restrict__ idxEA,
                                                 const int* __restrict__ idxEB,
                                                 const int* __restrict__ idxHA,
                                                 const int* __restrict__ idxHB,
                                                 float* __restrict__ dEA,
                                                 float* __restrict__ dEB,
                                                 float* __restrict__ dHA,
                                                 float* __restrict__ dHB) {
  int blk = blockIdx.x;
  const int* idx; float* dst; int K, rel;
  if (blk < 2400)      { idx = idxEA; dst = dEA; K = 150; rel = blk; }
  else if (blk < 4800) { idx = idxEB; dst = dEB; K = 150; rel = blk - 2400; }
  else if (blk < 5392) { idx = idxHA; dst = dHA; K = 37;  rel = blk - 4800; }
  else                 { idx = idxHB; dst = dHB; K = 37;  rel = blk - 5392; }
  int b = rel / K;
  int t = idx[rel];
  const float4* src = (const float4*)(emb + ((long)(b * 750 + t)) * 2048);
  float4* d = (float4*)(dst + (long)rel * 2048);
  for (int u = threadIdx.x; u < 512; u += 256) d[u] = src[u];
}

// ---------- video scores: per (b,c) mean of top-150 of cas[b,:,c] ----------
__global__ __launch_bounds__(256) void vtop_k(const float* __restrict__ cas,
                                              float* __restrict__ s) {
  __shared__ float v[1024];
  int b = blockIdx.x / 20, c = blockIdx.x - b * 20;
  int tid = threadIdx.x;
  for (int i = tid; i < 1024; i += 256)
    v[i] = (i < 750) ? cas[((long)(b * 750 + i)) * 20 + c] : -1.f;
  __syncthreads();
  for (int k = 2; k <= 1024; k <<= 1) {
    for (int j = k >> 1; j > 0; j >>= 1) {
      for (int i = tid; i < 1024; i += 256) {
        int ixj = i ^ j;
        if (ixj > i) {
          float a = v[i], cc = v[ixj];
          bool sw = ((i & k) == 0) ? (a < cc) : (a > cc);
          if (sw) { v[i] = cc; v[ixj] = a; }
        }
      }
      __syncthreads();
    }
  }
  if (tid == 0) {
    float sum = 0.f;
    for (int i = 0; i < 150; ++i) sum += v[i];
    s[b * 20 + c] = sum / 150.f;
  }
}

__global__ __launch_bounds__(64) void softmax20_k(const float* __restrict__ s,
                                                  float* __restrict__ out) {
  int b = blockIdx.x;
  if (threadIdx.x != 0) return;
  float mx = -3.4e38f;
  for (int c = 0; c < 20; ++c) mx = fmaxf(mx, s[b * 20 + c]);
  float e[20]; float sum = 0.f;
  for (int c = 0; c < 20; ++c) { e[c] = expf(s[b * 20 + c] - mx); sum += e[c]; }
  for (int c = 0; c < 20; ++c) out[b * 20 + c] = e[c] / sum;
}

// ---------- attention scores + softmax ----------
// One 4-wave block per (call,b,h): wave wv handles qi = wv, wv+4, ...
// K-panel (37x512) stays L2-hot across the block instead of being re-read
// by 37 independent waves. Per-qi math identical to the old kernel.
__global__ __launch_bounds__(256) void attn_scores_k(const float* __restrict__ q10,
                                                     int head0,
                                                     float* __restrict__ attnb) {
  int hl = blockIdx.y >> 1, call = blockIdx.y & 1;
  int head = head0 + hl;
  int iA = PIDX[head][0], iB = PIDX[head][1];
  const float* q  = q10 + (long)(call ? iA : iB) * 592 * 6144;
  const float* kv = q10 + (long)(call ? iB : iA) * 592 * 6144;
  int b = blockIdx.x >> 2, h = blockIdx.x & 3;
  int wv = threadIdx.x >> 6, lane = threadIdx.x & 63;
  __shared__ float sc[4][37];
  const float scale = 0.04419417382415922f;   // 1/sqrt(512)
  const float* kbase = kv + ((long)(b * 37)) * 6144 + 2048 + h * 512;
  long outbase = (((long)(((hl * 2 + call) * 16 + b) * 4 + h)) * 37) * 37;
  for (int qi = wv; qi < 37; qi += 4) {
    const float* qp = q + ((long)(b * 37 + qi)) * 6144 + h * 512;
    float qr[8];
#pragma unroll
    for (int j = 0; j < 8; ++j) qr[j] = qp[lane + 64 * j] * scale;
    for (int ki = 0; ki < 37; ++ki) {
      const float* kp = kbase + (long)ki * 6144;
      float d = 0.f;
#pragma unroll
      for (int j = 0; j < 8; ++j) d = fmaf(qr[j], kp[lane + 64 * j], d);
      for (int off = 32; off > 0; off >>= 1) d += __shfl_down(d, off, 64);
      if (lane == 0) sc[wv][ki] = d;
    }
    float v = (lane < 37) ? sc[wv][lane] : -3.4e38f;
    float mx = v;
    for (int off = 32; off > 0; off >>= 1) mx = fmaxf(mx, __shfl_xor(mx, off, 64));
    float e = (lane < 37) ? expf(v - mx) : 0.f;
    float sum = e;
    for (int off = 32; off > 0; off >>= 1) sum += __shfl_xor(sum, off, 64);
    if (lane < 37)
      attnb[outbase + (long)qi * 37 + lane] = e / sum;
  }
}

// ---------- attn @ V ----------
// One block per (call,b, qi-group of 8): V-panel (37x2048) read once per 8 qi.
// at[h][ki][q] layout -> broadcast float4 LDS reads, conflict-free.
// Per-output ki accumulation order identical to the old kernel.
__global__ __launch_bounds__(256) void attn_v_k(const float* __restrict__ q10,
                                                int head0,
                                                const float* __restrict__ attnb,
                                                float* __restrict__ obuf) {
  int hl = blockIdx.y >> 1, call = blockIdx.y & 1;
  int head = head0 + hl;
  int iA = PIDX[head][0], iB = PIDX[head][1];
  const float* kv = q10 + (long)(call ? iB : iA) * 592 * 6144;
  int b = blockIdx.x / 5, qg = blockIdx.x - b * 5;
  int tid = threadIdx.x;
  __shared__ float at[4][37][8];
  long abase = ((long)(((hl * 2 + call) * 16 + b) * 4)) * 37 * 37;
  for (int idx = tid; idx < 4 * 37 * 8; idx += 256) {
    int q = idx & 7;
    int ki = (idx >> 3) % 37;
    int h = idx / (37 * 8);
    int qi = qg * 8 + q;
    float v = 0.f;
    if (qi < 37) v = attnb[abase + ((long)h * 37 + qi) * 37 + ki];
    at[h][ki][q] = v;
  }
  __syncthreads();
  int yoff = call ? 37 : 0;
  const float* vbase = kv + ((long)(b * 37)) * 6144 + 4096;
  float* obase = obuf + (long)hl * (16L * 74 * 2048) + ((long)(b * 74 + yoff)) * 2048;
#pragma unroll 1
  for (int i = 0; i < 8; ++i) {
    int c = tid + 256 * i;
    int h = c >> 9;
    float acc[8] = {0.f, 0.f, 0.f, 0.f, 0.f, 0.f, 0.f, 0.f};
#pragma unroll 1
    for (int ki = 0; ki < 37; ++ki) {
      float vv = vbase[(long)ki * 6144 + c];
      float4 a0 = *(const float4*)&at[h][ki][0];
      float4 a1 = *(const float4*)&at[h][ki][4];
      acc[0] = fmaf(a0.x, vv, acc[0]);
      acc[1] = fmaf(a0.y, vv, acc[1]);
      acc[2] = fmaf(a0.z, vv, acc[2]);
      acc[3] = fmaf(a0.w, vv, acc[3]);
      acc[4] = fmaf(a1.x, vv, acc[4]);
      acc[5] = fmaf(a1.y, vv, acc[5]);
      acc[6] = fmaf(a1.z, vv, acc[6]);
      acc[7] = fmaf(a1.w, vv, acc[7]);
    }
#pragma unroll
    for (int q = 0; q < 8; ++q) {
      int qi = qg * 8 + q;
      if (qi < 37) obase[(long)qi * 2048 + c] = acc[q];
    }
  }
}

// ---------- l1 (74->10) + leaky + l2 (320->1) + sigmoid ----------
__global__ __launch_bounds__(320) void head_tail_k(const float* __restrict__ c2o,
                                                   const float* __restrict__ l1w,
                                                   const float* __restrict__ l1b,
                                                   const float* __restrict__ l2w,
                                                   const float* __restrict__ l2b,
                                                   float* __restrict__ out) {
  __shared__ float h[320];
  int blk = blockIdx.x, tid = threadIdx.x;
  int c = tid / 10, j = tid - c * 10;
  float acc = l1b[j];
  for (int l = 0; l < 74; ++l)
    acc = fmaf(c2o[((long)(blk * 74 + l)) * 32 + c], l1w[j * 74 + l], acc);
  acc = leaky_f(acc);
  h[c * 10 + j] = acc * l2w[c * 10 + j];
  __syncthreads();
  if (tid == 0) {
    float s = l2b[0];
    for (int i = 0; i < 320; ++i) s += h[i];
    out[blk] = 1.f / (1.f + expf(-s));
  }
}

// ---------------------------------------------------------------------------
extern "C" void kernel_launch(void* const* d_in, const int* in_sizes, int n_in,
                              void* d_out, int out_size, void* d_ws, size_t ws_size,
                              hipStream_t stream) {
  const float* x       = (const float*)d_in[0];
  const float* w_embed = (const float*)d_in[1];
  const float* b_embed = (const float*)d_in[2];
  const float* w_cls   = (const float*)d_in[3];
  const float* tf1_w   = (const float*)d_in[4];
  const float* tf1_b   = (const float*)d_in[5];
  const float* tf2_w   = (const float*)d_in[6];
  const float* tf2_b   = (const float*)d_in[7];
  const float* in_w    = (const float*)d_in[8];
  const float* in_b    = (const float*)d_in[9];
  const float* out_w   = (const float*)d_in[10];
  const float* out_b   = (const float*)d_in[11];
  const float* c1_w    = (const float*)d_in[12];
  const float* c1_b    = (const float*)d_in[13];
  const float* c2_w    = (const float*)d_in[14];
  const float* c2_b    = (const float*)d_in[15];
  const float* l1_w    = (const float*)d_in[16];
  const float* l1_b    = (const float*)d_in[17];
  const float* l2_w    = (const float*)d_in[18];
  const float* l2_b    = (const float*)d_in[19];
  float* out = (float*)d_out;
  float* ws  = (float*)d_ws;

  // output offsets (floats)
  const long O_VS = 0, O_ACT = 320, O_A2 = 12320, O_CAS = 24320, O_RH = 264320;
  const long O_EA = 264512;
  const long O_EB = O_EA + 16L * 150 * 2048;
  const long O_HA = O_EB + 16L * 150 * 2048;
  const long O_HB = O_HA + 16L * 37 * 2048;

  // ---- workspace layout (floats) — same footprint as round 6 ----
  long o = 0;
  float* emb   = ws + o; o += 12000L * 2048;
  f16*   embWf = (f16*)(ws + o); o += 12582912;
  float* q10   = ws;                                   // aliases emb+embWf (dead by then)
  f16*   c1Wf  = (f16*)(ws + o); o += 786432;
  float* wpk2  = ws + o; o += 3L * 32 * 128;
  float* arev  = ws + o; o += 12000;
  float* hsa   = ws + o; o += 12000;
  float* hsb   = ws + o; o += 12000;
  float* med   = ws + o; o += 16;
  float* mxv   = ws + o; o += 16;
  float* vsbuf = ws + o; o += 320;
  int* idxEA = (int*)(ws + o); o += 2400;
  int* idxEB = (int*)(ws + o); o += 2400;
  int* idxHA = (int*)(ws + o); o += 592;
  int* idxHB = (int*)(ws + o); o += 592;
  long oTail = o;
  (void)in_sizes; (void)n_in; (void)out_size;

  const long SZ_ATTNB12 = 12L * 2 * 16 * 4 * 37 * 37;
  const long SZ_OBUF12  = 12L * 16 * 74 * 2048;
  const long SZ_C1O12   = 14208L * 128;
  const long SZ_C2O12   = 14208L * 32;
  long needB = oTail + SZ_ATTNB12 + SZ_OBUF12 + SZ_C1O12 + SZ_C2O12;
  bool batched = (ws_size >= (size_t)needB * 4);

  // 1. pack conv weights (fragment-linear f16 hi/lo for MFMA paths)
  pack_frag_w_k<<<(12582912 + 255) / 256, 256, 0, stream>>>(w_embed, embWf, 2048, 2048, 3);
  pack_frag_w_k<<<(786432 + 255) / 256, 256, 0, stream>>>(c1_w, c1Wf, 128, 2048, 3);
  pack_w_k<<<(12288 + 255) / 256, 256, 0, stream>>>(c2_w, wpk2, 32, 128, 3);

  // 2. embed conv (k3, 2048->2048) + relu — MFMA f16x3, dbuf-A single-barrier.
  //    MFMA order bit-identical to round 6 (selection-safe).
  gemmf3_k<<<1504, 256, 0, stream>>>(x, embWf, b_embed, emb,
      12000, 2048, 2048, 3, -1, 750, 94, 1, 1);

  // 3. cas (1x1, 2048->20) + relu — exact fp64-accum path (selection-critical)
  gemm32_k<1><<<dim3(1, 375), 256, 0, stream>>>(emb, w_cls, nullptr, out + O_CAS,
      12000, 20, 2048, 1, 0, 750, 1536000L, 750, 15000L, 1);

  // 4. actionness, a2
  actionness_k<<<47, 256, 0, stream>>>(out + O_CAS, out + O_ACT);
  a2_k<<<16, 256, 0, stream>>>(out + O_ACT, tf1_w, tf1_b, tf2_w, tf2_b, out + O_A2);

  // 5. video scores
  vtop_k<<<320, 256, 0, stream>>>(out + O_CAS, vsbuf);
  softmax20_k<<<16, 64, 0, stream>>>(vsbuf, out + O_VS);

  // 6. selections (sort1 -> morph -> fused sort3 -> fused gather4)
  sort_topk_k<<<16, 256, 0, stream>>>(out + O_ACT, idxEA, 150, med, mxv);
  morph_k<<<16, 256, 0, stream>>>(out + O_ACT, med, mxv, arev, hsa, hsb);
  sort3_k<<<48, 256, 0, stream>>>(arev, hsa, hsb, idxEB, idxHA, idxHB);
  gather4_k<<<5984, 256, 0, stream>>>(emb, idxEA, idxEB, idxHA, idxHB,
      out + O_EA, out + O_EB, out + O_HA, out + O_HB);

  // 7. qkv projection for ALL 10 distinct head inputs (emb/embWf dead now)
  gemmx3_k<1><<<dim3(48, 47), 256, 0, stream>>>(out, in_w, in_b, q10,
      5920, 6144, 2048, O_EA, O_EB, O_HA, O_HB);

  // 8. relational heads
  if (batched) {
    float* attnbB = ws + oTail;
    float* obufB  = attnbB + SZ_ATTNB12;
    float* c1oB   = obufB + SZ_OBUF12;
    float* c2oB   = c1oB + SZ_C1O12;
    float* ybufB  = ws;               // aliases q10 region (dead after attn_v)

    attn_scores_k<<<dim3(64, 24), 256, 0, stream>>>(q10, 0, attnbB);
    attn_v_k<<<dim3(80, 24), 256, 0, stream>>>(q10, 0, attnbB, obufB);
    gemmx3_k<0><<<dim3(16, 111), 256, 0, stream>>>(obufB, out_w, out_b, ybufB,
        14208, 2048, 2048, 0, 0, 0, 0);
    gemmf3_k<<<111, 256, 0, stream>>>(ybufB, c1Wf, c1_b, c1oB,
        14208, 128, 2048, 3, -1, 74, 111, 0, 2);
    gemm32_k<0><<<dim3(1, 444), 256, 0, stream>>>(c1oB, wpk2, c2_b, c2oB,
        14208, 32, 128, 3, -1, 74, 74L * 128, 74, 74L * 32, 2);
    head_tail_k<<<192, 320, 0, stream>>>(c2oB, l1_w, l1_b, l2_w, l2_b, out + O_RH);
  } else {
    // legacy per-head loop
    float* attnbL = ws + oTail;
    float* obufL  = attnbL + 2L * 16 * 4 * 37 * 37;
    float* ybufL  = obufL + 16L * 74 * 2048;
    float* c1oL   = ybufL + 16L * 74 * 2048;
    float* c2oL   = c1oL + 1184L * 128;
    for (int i = 0; i < 12; ++i) {
      attn_scores_k<<<dim3(64, 2), 256, 0, stream>>>(q10, i, attnbL);
      attn_v_k<<<dim3(80, 2), 256, 0, stream>>>(q10, i, attnbL, obufL);
      gemmx3_k<0><<<dim3(16, 10), 256, 0, stream>>>(obufL, out_w, out_b, ybufL,
          1184, 2048, 2048, 0, 0, 0, 0);
      gemmf3_k<<<10, 256, 0, stream>>>(ybufL, c1Wf, c1_b, c1oL,
          1184, 128, 2048, 3, -1, 74, 10, 0, 2);
      gemm32_k<0><<<dim3(1, 37), 256, 0, stream>>>(c1oL, wpk2, c2_b, c2oL,
          1184, 32, 128, 3, -1, 74, 74L * 128, 74, 74L * 32, 2);
      head_tail_k<<<16, 320, 0, stream>>>(c2oL, l1_w, l1_b, l2_w, l2_b, out + O_RH + 16L * i);
    }
  }
}